// Round 7
// baseline (356.198 us; speedup 1.0000x reference)
//
#include <hip/hip_runtime.h>
#include <math.h>

#define NEG_SLOPE 0.2f
#define LN_EPS 1e-5f
#define NWG 48          // scatter workgroups; hist = [NB][NWG]

typedef __attribute__((ext_vector_type(8))) short bf16x8;
typedef __attribute__((ext_vector_type(4))) float f32x4;

__device__ __forceinline__ float lrelu(float v){ return v > 0.f ? v : NEG_SLOPE * v; }
__device__ __forceinline__ float eluf (float v){ return v > 0.f ? v : expm1f(v); }

__device__ __forceinline__ unsigned short f2bf(float f){
    unsigned x = __float_as_uint(f);
    unsigned r = (x + 0x7fffu + ((x >> 16) & 1u)) >> 16;   // round-nearest-even
    return (unsigned short)r;
}
__device__ __forceinline__ float bf_lo(unsigned u){ return __uint_as_float(u << 16); }
__device__ __forceinline__ float bf_hi(unsigned u){ return __uint_as_float(u & 0xffff0000u); }

// ---------------- bucketed CSR build, atomic-free scatter ----------------

__global__ __launch_bounds__(512) void k_hist(
    const int* __restrict__ dst, int* __restrict__ hist, int E, int NB, int chunk)
{
    __shared__ int cnt[2048];
    int t = threadIdx.x, w = blockIdx.x;
    for (int i = t; i < NB; i += 512) cnt[i] = 0;
    __syncthreads();
    int e0 = w * chunk, e1 = min(E, e0 + chunk);
    for (int e = e0 + t; e < e1; e += 512)
        atomicAdd(&cnt[dst[e] >> 6], 1);
    __syncthreads();
    for (int i = t; i < NB; i += 512)
        hist[i * NWG + w] = cnt[i];
}

__global__ void k_chunk_sum(const int* __restrict__ data, int* __restrict__ partial, int M){
    __shared__ int lds[256];
    int t = threadIdx.x;
    int v = blockIdx.x * 256 + t;
    lds[t] = (v < M) ? data[v] : 0;
    __syncthreads();
    for (int s = 128; s > 0; s >>= 1){
        if (t < s) lds[t] += lds[t + s];
        __syncthreads();
    }
    if (t == 0) partial[blockIdx.x] = lds[0];
}

__global__ void k_scan_partial(int* __restrict__ partial, int n){
    __shared__ int lds[512];
    int t = threadIdx.x;
    int x = (t < n) ? partial[t] : 0;
    lds[t] = x;
    __syncthreads();
    for (int s = 1; s < 512; s <<= 1){
        int a = (t >= s) ? lds[t - s] : 0;
        __syncthreads();
        lds[t] += a;
        __syncthreads();
    }
    if (t < n) partial[t] = lds[t] - x;   // exclusive
}

__global__ void k_scan_apply(int* __restrict__ data, const int* __restrict__ partial, int M){
    __shared__ int lds[256];
    int t = threadIdx.x;
    int v = blockIdx.x * 256 + t;
    int x = (v < M) ? data[v] : 0;
    lds[t] = x;
    __syncthreads();
    for (int s = 1; s < 256; s <<= 1){
        int a = (t >= s) ? lds[t - s] : 0;
        __syncthreads();
        lds[t] += a;
        __syncthreads();
    }
    if (v < M) data[v] = partial[blockIdx.x] + lds[t] - x;   // exclusive
}

__global__ __launch_bounds__(512) void k_pscatter(
    const int* __restrict__ src, const int* __restrict__ dst,
    const int* __restrict__ shist, unsigned* __restrict__ ebuf, int E, int NB, int chunk)
{
    __shared__ int cur[2048];
    int t = threadIdx.x, w = blockIdx.x;
    for (int i = t; i < NB; i += 512) cur[i] = shist[i * NWG + w];
    __syncthreads();
    int e0 = w * chunk, e1 = min(E, e0 + chunk);
    for (int e = e0 + t; e < e1; e += 512){
        int d = dst[e];
        int pos = atomicAdd(&cur[d >> 6], 1);
        ebuf[pos] = ((unsigned)(d & 63) << 26) | (unsigned)src[e];
    }
}

// one wave per bucket: local degree count -> wave-scan -> row_ptr + LDS-cursor fill
__global__ __launch_bounds__(256) void k_bfill(
    const unsigned* __restrict__ ebuf, const int* __restrict__ shist,
    int* __restrict__ row_ptr, int* __restrict__ col, int N, int NB, int E)
{
    __shared__ int scnt[4][64];
    int t = threadIdx.x, lane = t & 63, w = t >> 6;
    int b = blockIdx.x * 4 + w;
    bool act = b < NB;
    if (t == 0 && blockIdx.x == 0) row_ptr[N] = E;
    scnt[w][lane] = 0;
    __syncthreads();
    int ebeg = 0, eend = 0;
    if (act){
        ebeg = shist[b * NWG];
        eend = (b + 1 < NB) ? shist[(b + 1) * NWG] : E;
    }
    for (int j = ebeg + lane; j < eend; j += 64)
        atomicAdd(&scnt[w][ebuf[j] >> 26], 1);
    __syncthreads();
    int deg = scnt[w][lane];
    int incl = deg;
    #pragma unroll
    for (int k = 1; k < 64; k <<= 1){
        int up = __shfl_up(incl, k);
        if (lane >= k) incl += up;
    }
    int excl = incl - deg;
    int base = act ? ebeg : 0;
    int v = b * 64 + lane;
    if (act && v < N) row_ptr[v] = base + excl;
    __syncthreads();
    scnt[w][lane] = base + excl;
    __syncthreads();
    for (int j = ebeg + lane; j < eend; j += 64){
        unsigned u = ebuf[j];
        int pos = atomicAdd(&scnt[w][u >> 26], 1);
        col[pos] = (int)(u & 0x03FFFFFFu);
    }
}

// ---------------- layer 1 attention logits: es/ed only ----------------

__global__ __launch_bounds__(256) void k_lin1(
    const float* __restrict__ x, const float* __restrict__ W1,
    const float* __restrict__ asrc, const float* __restrict__ adst,
    float* __restrict__ es, float* __restrict__ ed, int N)
{
    __shared__ float sW[384], sA[128], sB[128];
    int t = threadIdx.x;
    for (int i = t; i < 384; i += 256) sW[i] = W1[i];
    for (int i = t; i < 128; i += 256){ sA[i] = asrc[i]; sB[i] = adst[i]; }
    __syncthreads();
    int lane = t & 63;
    int v = blockIdx.x * 4 + (t >> 6);
    if (v >= N) return;
    float x0 = x[(size_t)v*3], x1 = x[(size_t)v*3+1], x2 = x[(size_t)v*3+2];
    int c = lane * 2;
    float h0 = x0*sW[c  ] + x1*sW[128+c  ] + x2*sW[256+c  ];
    float h1 = x0*sW[c+1] + x1*sW[128+c+1] + x2*sW[256+c+1];
    int hsel = lane >> 4;
    float ts = h0*sA[c] + h1*sA[c+1];
    float td = h0*sB[c] + h1*sB[c+1];
    #pragma unroll
    for (int m = 8; m >= 1; m >>= 1){
        ts += __shfl_xor(ts, m); td += __shfl_xor(td, m);
    }
    if ((lane & 15) == 0){
        es[(size_t)v*4 + hsel] = ts;
        ed[(size_t)v*4 + hsel] = td;
    }
}

// ---------------- layer 1: factored attn+agg ----------------
// sum_e p_e*(x[s]@W) = (sum_e p_e*x[s])@W : aggregate weighted 3-vector per head.
// lane = (head hsel = lane>>4, sub = lane&15); each lane streams its own edges.

__global__ __launch_bounds__(256) void k_agg1(
    const float* __restrict__ x, const float* __restrict__ W1,
    const float* __restrict__ es, const float* __restrict__ ed,
    const int* __restrict__ row_ptr, const int* __restrict__ col,
    const float* __restrict__ b1, const float* __restrict__ g1, const float* __restrict__ be1,
    unsigned* __restrict__ h1b, int N)
{
    int t = threadIdx.x, lane = t & 63, w = t >> 6;
    int v = blockIdx.x * 4 + w;
    if (v >= N) return;
    int hsel = lane >> 4, sub = lane & 15;
    float edh = ed[(size_t)v*4 + hsel];
    float sa0 = 0.f, sa1 = 0.f, sa2 = 0.f, sp_ = 0.f;
    int beg = row_ptr[v], end = row_ptr[v+1];
    for (int j = beg + sub; j < end; j += 16){
        int s = col[j];
        float q = es[(size_t)s*4 + hsel];
        float p = __expf(lrelu(q + edh));
        const float* xp = x + (size_t)s*3;
        sp_ += p;
        sa0 += p*xp[0]; sa1 += p*xp[1]; sa2 += p*xp[2];
    }
    if (sub == 0){   // self loop, once per head
        float p = __expf(lrelu(es[(size_t)v*4 + hsel] + edh));
        const float* xp = x + (size_t)v*3;
        sp_ += p;
        sa0 += p*xp[0]; sa1 += p*xp[1]; sa2 += p*xp[2];
    }
    #pragma unroll
    for (int k = 1; k < 16; k <<= 1){
        sa0 += __shfl_xor(sa0, k); sa1 += __shfl_xor(sa1, k);
        sa2 += __shfl_xor(sa2, k); sp_ += __shfl_xor(sp_, k);
    }
    float inv = 1.f / (sp_ + 1e-16f);
    float A0 = sa0*inv, A1 = sa1*inv, A2 = sa2*inv;
    int c = lane * 2;   // channels c,c+1 ; head (c>>5) == hsel
    float h0 = A0*W1[c  ] + A1*W1[128+c  ] + A2*W1[256+c  ];
    float h1v= A0*W1[c+1] + A1*W1[128+c+1] + A2*W1[256+c+1];
    float2 bb = *(const float2*)(b1 + c);
    float oA = eluf(h0 + bb.x);
    float oB = eluf(h1v + bb.y);
    float su = oA + oB;
    #pragma unroll
    for (int k = 32; k >= 1; k >>= 1) su += __shfl_xor(su, k);
    float mean = su * (1.f/128.f);
    float aA = oA - mean, aB = oB - mean;
    float vs = aA*aA + aB*aB;
    #pragma unroll
    for (int k = 32; k >= 1; k >>= 1) vs += __shfl_xor(vs, k);
    float rstd = rsqrtf(vs * (1.f/128.f) + LN_EPS);
    float2 gg = *(const float2*)(g1 + c);
    float2 ee = *(const float2*)(be1 + c);
    float rx = aA*rstd*gg.x + ee.x, ry = aB*rstd*gg.y + ee.y;
    h1b[(size_t)v*64 + lane] = (unsigned)f2bf(rx) | ((unsigned)f2bf(ry) << 16);
}

// ---------------- layer 2 linear via MFMA: h1b[N,128]bf16 @ W2[128,64] ----------------

__global__ __launch_bounds__(256) void k_lin2(
    const unsigned short* __restrict__ h1b,   // [N][128] bf16
    const float* __restrict__ W2,             // [128][64] fp32
    const float* __restrict__ asrc, const float* __restrict__ adst,
    unsigned short* __restrict__ hlin2b, float* __restrict__ es2, float* __restrict__ ed2, int N)
{
    int t = threadIdx.x, lane = t & 63, w = t >> 6;
    int vb = blockIdx.x * 64 + w * 16;
    if (vb >= N) return;
    int lo4 = lane & 15, hi4 = lane >> 4;

    int arow = vb + lo4; if (arow >= N) arow = N - 1;
    const unsigned short* ap = h1b + (size_t)arow*128 + hi4*8;
    bf16x8 a0 = *(const bf16x8*)(ap);
    bf16x8 a1 = *(const bf16x8*)(ap + 32);
    bf16x8 a2 = *(const bf16x8*)(ap + 64);
    bf16x8 a3 = *(const bf16x8*)(ap + 96);

    f32x4 acc[4];
    #pragma unroll
    for (int nt = 0; nt < 4; ++nt) acc[nt] = (f32x4){0.f, 0.f, 0.f, 0.f};

    #pragma unroll
    for (int nt = 0; nt < 4; ++nt){
        int cb = nt*16 + lo4;
        #pragma unroll
        for (int kt = 0; kt < 4; ++kt){
            const float* wp = W2 + (size_t)(kt*32 + hi4*8)*64 + cb;
            bf16x8 b;
            #pragma unroll
            for (int j = 0; j < 8; ++j) b[j] = (short)f2bf(wp[(size_t)j*64]);
            bf16x8 a = (kt==0) ? a0 : (kt==1) ? a1 : (kt==2) ? a2 : a3;
            acc[nt] = __builtin_amdgcn_mfma_f32_16x16x32_bf16(a, b, acc[nt], 0, 0, 0);
        }
    }

    float sa0 = asrc[lo4], sa1 = asrc[16+lo4], sa2 = asrc[32+lo4], sa3 = asrc[48+lo4];
    float sb0 = adst[lo4], sb1 = adst[16+lo4], sb2 = adst[32+lo4], sb3 = adst[48+lo4];

    #pragma unroll
    for (int reg = 0; reg < 4; ++reg){
        int nr = vb + hi4*4 + reg;
        bool ok = nr < N;
        float c0 = acc[0][reg], c1 = acc[1][reg], c2 = acc[2][reg], c3 = acc[3][reg];
        if (ok){
            unsigned short* hp = hlin2b + (size_t)nr*64 + lo4;
            hp[ 0] = f2bf(c0);
            hp[16] = f2bf(c1);
            hp[32] = f2bf(c2);
            hp[48] = f2bf(c3);
        }
        float ps0 = c0*sa0 + c1*sa1, ps1 = c2*sa2 + c3*sa3;
        float pd0 = c0*sb0 + c1*sb1, pd1 = c2*sb2 + c3*sb3;
        #pragma unroll
        for (int m = 8; m >= 1; m >>= 1){
            ps0 += __shfl_xor(ps0, m); ps1 += __shfl_xor(ps1, m);
            pd0 += __shfl_xor(pd0, m); pd1 += __shfl_xor(pd1, m);
        }
        if (ok && lo4 == 0){
            float2 e; e.x = ps0; e.y = ps1;
            float2 d; d.x = pd0; d.y = pd1;
            *(float2*)(es2 + (size_t)nr*2) = e;
            *(float2*)(ed2 + (size_t)nr*2) = d;
        }
    }
}

// ---------------- layer 2: fused attn+agg (8 edge slots x 8 lanes) ----------------
// lane = (slot g = lane>>3, l = lane&7); lane covers channels 8l..8l+7 (head l>>2)

__global__ __launch_bounds__(256) void k_agg2(
    const unsigned* __restrict__ h2b,          // [N][32] u32 = bf16[N][64]
    const float* __restrict__ es2, const float* __restrict__ ed2,
    const int* __restrict__ row_ptr, const int* __restrict__ col,
    const float* __restrict__ x, const float* __restrict__ Wskip, const float* __restrict__ bskip,
    const float* __restrict__ b2, const float* __restrict__ g2, const float* __restrict__ be2,
    float* __restrict__ h2, int N)
{
    __shared__ float sp[4][2][68];
    int t = threadIdx.x, lane = t & 63, w = t >> 6;
    int v = blockIdx.x * 4 + w;
    if (v >= N) return;
    int g = lane >> 3, l = lane & 7;
    int hsel = l >> 2;
    float2 edv = *(const float2*)(ed2 + (size_t)v*2);
    float2 esv = *(const float2*)(es2 + (size_t)v*2);
    float eh = (hsel ? esv.y : esv.x) + (hsel ? edv.y : edv.x);
    float pself = (g == 0) ? __expf(lrelu(eh)) : 0.f;
    uint4 us = *(const uint4*)(h2b + (size_t)v*32 + l*4);
    float acc[8];
    acc[0] = pself*bf_lo(us.x); acc[1] = pself*bf_hi(us.x);
    acc[2] = pself*bf_lo(us.y); acc[3] = pself*bf_hi(us.y);
    acc[4] = pself*bf_lo(us.z); acc[5] = pself*bf_hi(us.z);
    acc[6] = pself*bf_lo(us.w); acc[7] = pself*bf_hi(us.w);
    float sum_p = pself;

    int beg = row_ptr[v], end = row_ptr[v+1];
    for (int base = beg; base < end; base += 64){
        int cnt = min(64, end - base);
        int sreg = 0;
        if (lane < cnt){
            sreg = col[base + lane];
            float2 q = *(const float2*)(es2 + (size_t)sreg*2);
            sp[w][0][lane] = __expf(lrelu(q.x + edv.x));
            sp[w][1][lane] = __expf(lrelu(q.y + edv.y));
        }
        asm volatile("s_waitcnt lgkmcnt(0)" ::: "memory");
        for (int i = 0; i < cnt; i += 8){
            int e = i + g;
            bool val = e < cnt;
            int s = __shfl(sreg, e);
            if (!val) s = v;
            float p = val ? sp[w][hsel][e] : 0.f;
            uint4 u = *(const uint4*)(h2b + (size_t)s*32 + l*4);
            sum_p += p;
            acc[0] += p*bf_lo(u.x); acc[1] += p*bf_hi(u.x);
            acc[2] += p*bf_lo(u.y); acc[3] += p*bf_hi(u.y);
            acc[4] += p*bf_lo(u.z); acc[5] += p*bf_hi(u.z);
            acc[6] += p*bf_lo(u.w); acc[7] += p*bf_hi(u.w);
        }
    }
    // combine the 8 edge slots (lanes with same l)
    #pragma unroll
    for (int k = 8; k < 64; k <<= 1){
        #pragma unroll
        for (int j = 0; j < 8; ++j) acc[j] += __shfl_xor(acc[j], k);
        sum_p += __shfl_xor(sum_p, k);
    }
    float inv = 1.f / (sum_p + 1e-16f);
    #pragma unroll
    for (int j = 0; j < 8; ++j) acc[j] *= inv;
    // head mean: channel c (lane l<4) pairs with c+32 (lane l+4)
    float xa = x[(size_t)v*3], xb = x[(size_t)v*3+1], xc = x[(size_t)v*3+2];
    int cc = (l & 3) * 8;
    float z[8];
    #pragma unroll
    for (int j = 0; j < 8; ++j){
        float other = __shfl_xor(acc[j], 4);
        float o = eluf(0.5f*(acc[j] + other) + b2[cc+j]);
        float sk = xa*Wskip[cc+j] + xb*Wskip[32+cc+j] + xc*Wskip[64+cc+j] + bskip[cc+j];
        z[j] = o + sk;
    }
    float su = 0.f;
    #pragma unroll
    for (int j = 0; j < 8; ++j) su += z[j];
    su += __shfl_xor(su, 1); su += __shfl_xor(su, 2);
    float mean = su * (1.f/32.f);
    float vs = 0.f;
    #pragma unroll
    for (int j = 0; j < 8; ++j){ float d = z[j]-mean; vs += d*d; }
    vs += __shfl_xor(vs, 1); vs += __shfl_xor(vs, 2);
    float rstd = rsqrtf(vs * (1.f/32.f) + LN_EPS);
    if (g == 0 && l < 4){
        float4 r0, r1;
        r0.x = (z[0]-mean)*rstd*g2[cc  ] + be2[cc  ];
        r0.y = (z[1]-mean)*rstd*g2[cc+1] + be2[cc+1];
        r0.z = (z[2]-mean)*rstd*g2[cc+2] + be2[cc+2];
        r0.w = (z[3]-mean)*rstd*g2[cc+3] + be2[cc+3];
        r1.x = (z[4]-mean)*rstd*g2[cc+4] + be2[cc+4];
        r1.y = (z[5]-mean)*rstd*g2[cc+5] + be2[cc+5];
        r1.z = (z[6]-mean)*rstd*g2[cc+6] + be2[cc+6];
        r1.w = (z[7]-mean)*rstd*g2[cc+7] + be2[cc+7];
        *(float4*)(h2 + (size_t)v*32 + cc)     = r0;
        *(float4*)(h2 + (size_t)v*32 + cc + 4) = r1;
    }
}

// ---------------- pooling: per-graph mean/max/std (batch sorted) + projection ----------------

__global__ __launch_bounds__(256) void k_pool(
    const float* __restrict__ h2, const int* __restrict__ batch,
    const float* __restrict__ Wp, const float* __restrict__ bp,
    float* __restrict__ out, int N)
{
    int g = blockIdx.x; int t = threadIdx.x;
    __shared__ int sBeg, sEnd;
    if (t == 0){
        int lo = 0, hi = N;
        while (lo < hi){ int mid = (lo+hi) >> 1; if (batch[mid] < g) lo = mid+1; else hi = mid; }
        sBeg = lo;
        lo = sBeg; hi = N;
        while (lo < hi){ int mid = (lo+hi) >> 1; if (batch[mid] < g+1) lo = mid+1; else hi = mid; }
        sEnd = lo;
    }
    __syncthreads();
    int beg = sBeg, end = sEnd;
    int ch = t & 31, grp = t >> 5;
    float sum = 0.f, sq = 0.f, mx = -INFINITY;
    for (int i = beg + grp; i < end; i += 8){
        float val = h2[(size_t)i*32 + ch];
        sum += val; sq += val*val; mx = fmaxf(mx, val);
    }
    __shared__ float lsum[256], lsq[256], lmx[256];
    lsum[t] = sum; lsq[t] = sq; lmx[t] = mx;
    __syncthreads();
    for (int s = 4; s >= 1; s >>= 1){
        if (grp < s){
            lsum[t] += lsum[t + s*32];
            lsq [t] += lsq [t + s*32];
            lmx [t]  = fmaxf(lmx[t], lmx[t + s*32]);
        }
        __syncthreads();
    }
    __shared__ float feat[96];
    if (t < 32){
        float cnt = fmaxf((float)(end - beg), 1.f);
        float mean = lsum[t] / cnt;
        float var  = lsq[t] / cnt - mean*mean;
        feat[t]      = mean;
        feat[32 + t] = lmx[t];
        feat[64 + t] = sqrtf(fmaxf(var, 0.f));
    }
    __syncthreads();
    if (t < 48){
        float acc = bp[t];
        #pragma unroll 8
        for (int k = 0; k < 96; ++k) acc += feat[k] * Wp[k*48 + t];
        out[(size_t)g*48 + t] = acc;
    }
}

// ---------------- launcher ----------------

extern "C" void kernel_launch(void* const* d_in, const int* in_sizes, int n_in,
                              void* d_out, int out_size, void* d_ws, size_t ws_size,
                              hipStream_t stream)
{
    const float* x     = (const float*)d_in[0];
    const int*   ei    = (const int*)  d_in[1];
    const int*   batch = (const int*)  d_in[2];
    const float* W1    = (const float*)d_in[3];
    const float* as1   = (const float*)d_in[4];
    const float* ad1   = (const float*)d_in[5];
    const float* b1    = (const float*)d_in[6];
    const float* W2    = (const float*)d_in[7];
    const float* as2   = (const float*)d_in[8];
    const float* ad2   = (const float*)d_in[9];
    const float* b2    = (const float*)d_in[10];
    const float* Wskip = (const float*)d_in[11];
    const float* bskip = (const float*)d_in[12];
    const float* g1    = (const float*)d_in[13];
    const float* be1   = (const float*)d_in[14];
    const float* g2    = (const float*)d_in[15];
    const float* be2   = (const float*)d_in[16];
    const float* Wp    = (const float*)d_in[17];
    const float* bp    = (const float*)d_in[18];

    int N = in_sizes[0] / 3;
    int E = in_sizes[1] / 2;
    int B = out_size / 48;
    const int* src = ei;
    const int* dst = ei + E;
    int NBUK = (N + 63) / 64;
    int chunk = (E + NWG - 1) / NWG;
    int M = NBUK * NWG;

    char* w = (char*)d_ws;
    auto alloc = [&](size_t bytes) -> char* {
        char* p = w; w += (bytes + 255) & ~(size_t)255; return p;
    };
    int*   row_ptr = (int*)  alloc((size_t)(N+1)*4);
    int*   hist    = (int*)  alloc((size_t)M*4);
    int*   partial = (int*)  alloc(4*1024);
    int*   col     = (int*)  alloc((size_t)E*4);
    unsigned* h2b  = (unsigned*)alloc((size_t)N*32*4); // bf16[N][64] layer2 staging
    float* es      = (float*)alloc((size_t)N*4*4);
    float* ed      = (float*)alloc((size_t)N*4*4);
    unsigned* h1b  = (unsigned*)alloc((size_t)N*64*4); // bf16[N][128]
    float* h2      = (float*)alloc((size_t)N*32*4);
    unsigned* ebuf = (unsigned*)h2;                    // alias: ebuf dead before agg2 writes h2
    (void)ws_size;

    int mb  = (M + 255) / 256;
    int nb  = (N + 3) / 4;
    int nb2 = (N + 63) / 64;

    k_hist        <<<NWG, 512, 0, stream>>>(dst, hist, E, NBUK, chunk);
    k_chunk_sum   <<<mb, 256, 0, stream>>>(hist, partial, M);
    k_scan_partial<<<1, 512, 0, stream>>>(partial, mb);
    k_scan_apply  <<<mb, 256, 0, stream>>>(hist, partial, M);
    k_pscatter    <<<NWG, 512, 0, stream>>>(src, dst, hist, ebuf, E, NBUK, chunk);
    k_bfill       <<<(NBUK + 3) / 4, 256, 0, stream>>>(ebuf, hist, row_ptr, col, N, NBUK, E);

    k_lin1 <<<nb, 256, 0, stream>>>(x, W1, as1, ad1, es, ed, N);
    k_agg1 <<<nb, 256, 0, stream>>>(x, W1, es, ed, row_ptr, col, b1, g1, be1, h1b, N);
    k_lin2 <<<nb2, 256, 0, stream>>>((const unsigned short*)h1b, W2, as2, ad2,
                                     (unsigned short*)h2b, es, ed, N);
    k_agg2 <<<nb, 256, 0, stream>>>(h2b, es, ed, row_ptr, col,
                                    x, Wskip, bskip, b2, g2, be2, h2, N);
    k_pool <<<B, 256, 0, stream>>>(h2, batch, Wp, bp, (float*)d_out, N);
}

// Round 8
// 302.817 us; speedup vs baseline: 1.1763x; 1.1763x over previous
//
#include <hip/hip_runtime.h>
#include <math.h>

#define NEG_SLOPE 0.2f
#define LN_EPS 1e-5f
#define NWG 48          // scatter workgroups; hist = [NB][NWG]

typedef __attribute__((ext_vector_type(8))) short bf16x8;
typedef __attribute__((ext_vector_type(4))) float f32x4;

__device__ __forceinline__ float lrelu(float v){ return v > 0.f ? v : NEG_SLOPE * v; }
__device__ __forceinline__ float eluf (float v){ return v > 0.f ? v : expm1f(v); }

__device__ __forceinline__ unsigned short f2bf(float f){
    unsigned x = __float_as_uint(f);
    unsigned r = (x + 0x7fffu + ((x >> 16) & 1u)) >> 16;   // round-nearest-even
    return (unsigned short)r;
}
__device__ __forceinline__ float bf_lo(unsigned u){ return __uint_as_float(u << 16); }
__device__ __forceinline__ float bf_hi(unsigned u){ return __uint_as_float(u & 0xffff0000u); }

// ---------------- bucketed CSR build, atomic-free scatter ----------------

__global__ __launch_bounds__(512) void k_hist(
    const int* __restrict__ dst, int* __restrict__ hist, int E, int NB, int chunk)
{
    __shared__ int cnt[2048];
    int t = threadIdx.x, w = blockIdx.x;
    for (int i = t; i < NB; i += 512) cnt[i] = 0;
    __syncthreads();
    int e0 = w * chunk, e1 = min(E, e0 + chunk);
    for (int e = e0 + t; e < e1; e += 512)
        atomicAdd(&cnt[dst[e] >> 6], 1);
    __syncthreads();
    for (int i = t; i < NB; i += 512)
        hist[i * NWG + w] = cnt[i];
}

__global__ void k_chunk_sum(const int* __restrict__ data, int* __restrict__ partial, int M){
    __shared__ int lds[256];
    int t = threadIdx.x;
    int v = blockIdx.x * 256 + t;
    lds[t] = (v < M) ? data[v] : 0;
    __syncthreads();
    for (int s = 128; s > 0; s >>= 1){
        if (t < s) lds[t] += lds[t + s];
        __syncthreads();
    }
    if (t == 0) partial[blockIdx.x] = lds[0];
}

__global__ void k_scan_partial(int* __restrict__ partial, int n){
    __shared__ int lds[512];
    int t = threadIdx.x;
    int x = (t < n) ? partial[t] : 0;
    lds[t] = x;
    __syncthreads();
    for (int s = 1; s < 512; s <<= 1){
        int a = (t >= s) ? lds[t - s] : 0;
        __syncthreads();
        lds[t] += a;
        __syncthreads();
    }
    if (t < n) partial[t] = lds[t] - x;   // exclusive
}

__global__ void k_scan_apply(int* __restrict__ data, const int* __restrict__ partial, int M){
    __shared__ int lds[256];
    int t = threadIdx.x;
    int v = blockIdx.x * 256 + t;
    int x = (v < M) ? data[v] : 0;
    lds[t] = x;
    __syncthreads();
    for (int s = 1; s < 256; s <<= 1){
        int a = (t >= s) ? lds[t - s] : 0;
        __syncthreads();
        lds[t] += a;
        __syncthreads();
    }
    if (v < M) data[v] = partial[blockIdx.x] + lds[t] - x;   // exclusive
}

__global__ __launch_bounds__(512) void k_pscatter(
    const int* __restrict__ src, const int* __restrict__ dst,
    const int* __restrict__ shist, unsigned* __restrict__ ebuf, int E, int NB, int chunk)
{
    __shared__ int cur[2048];
    int t = threadIdx.x, w = blockIdx.x;
    for (int i = t; i < NB; i += 512) cur[i] = shist[i * NWG + w];
    __syncthreads();
    int e0 = w * chunk, e1 = min(E, e0 + chunk);
    for (int e = e0 + t; e < e1; e += 512){
        int d = dst[e];
        int pos = atomicAdd(&cur[d >> 6], 1);
        ebuf[pos] = ((unsigned)(d & 63) << 26) | (unsigned)src[e];
    }
}

// one wave per bucket: local degree count -> wave-scan -> row_ptr + LDS-cursor fill
__global__ __launch_bounds__(256) void k_bfill(
    const unsigned* __restrict__ ebuf, const int* __restrict__ shist,
    int* __restrict__ row_ptr, int* __restrict__ col, int N, int NB, int E)
{
    __shared__ int scnt[4][64];
    int t = threadIdx.x, lane = t & 63, w = t >> 6;
    int b = blockIdx.x * 4 + w;
    bool act = b < NB;
    if (t == 0 && blockIdx.x == 0) row_ptr[N] = E;
    scnt[w][lane] = 0;
    __syncthreads();
    int ebeg = 0, eend = 0;
    if (act){
        ebeg = shist[b * NWG];
        eend = (b + 1 < NB) ? shist[(b + 1) * NWG] : E;
    }
    for (int j = ebeg + lane; j < eend; j += 64)
        atomicAdd(&scnt[w][ebuf[j] >> 26], 1);
    __syncthreads();
    int deg = scnt[w][lane];
    int incl = deg;
    #pragma unroll
    for (int k = 1; k < 64; k <<= 1){
        int up = __shfl_up(incl, k);
        if (lane >= k) incl += up;
    }
    int excl = incl - deg;
    int base = act ? ebeg : 0;
    int v = b * 64 + lane;
    if (act && v < N) row_ptr[v] = base + excl;
    __syncthreads();
    scnt[w][lane] = base + excl;
    __syncthreads();
    for (int j = ebeg + lane; j < eend; j += 64){
        unsigned u = ebuf[j];
        int pos = atomicAdd(&scnt[w][u >> 26], 1);
        col[pos] = (int)(u & 0x03FFFFFFu);
    }
}

// ---------------- layer 1 attention logits: es/ed only ----------------

__global__ __launch_bounds__(256) void k_lin1(
    const float* __restrict__ x, const float* __restrict__ W1,
    const float* __restrict__ asrc, const float* __restrict__ adst,
    float* __restrict__ es, float* __restrict__ ed, int N)
{
    __shared__ float sW[384], sA[128], sB[128];
    int t = threadIdx.x;
    for (int i = t; i < 384; i += 256) sW[i] = W1[i];
    for (int i = t; i < 128; i += 256){ sA[i] = asrc[i]; sB[i] = adst[i]; }
    __syncthreads();
    int lane = t & 63;
    int v = blockIdx.x * 4 + (t >> 6);
    if (v >= N) return;
    float x0 = x[(size_t)v*3], x1 = x[(size_t)v*3+1], x2 = x[(size_t)v*3+2];
    int c = lane * 2;
    float h0 = x0*sW[c  ] + x1*sW[128+c  ] + x2*sW[256+c  ];
    float h1 = x0*sW[c+1] + x1*sW[128+c+1] + x2*sW[256+c+1];
    int hsel = lane >> 4;
    float ts = h0*sA[c] + h1*sA[c+1];
    float td = h0*sB[c] + h1*sB[c+1];
    #pragma unroll
    for (int m = 8; m >= 1; m >>= 1){
        ts += __shfl_xor(ts, m); td += __shfl_xor(td, m);
    }
    if ((lane & 15) == 0){
        es[(size_t)v*4 + hsel] = ts;
        ed[(size_t)v*4 + hsel] = td;
    }
}

// ---------------- layer 1: factored attn+agg ----------------
// sum_e p_e*(x[s]@W) = (sum_e p_e*x[s])@W : aggregate weighted 3-vector per head.

__global__ __launch_bounds__(256) void k_agg1(
    const float* __restrict__ x, const float* __restrict__ W1,
    const float* __restrict__ es, const float* __restrict__ ed,
    const int* __restrict__ row_ptr, const int* __restrict__ col,
    const float* __restrict__ b1, const float* __restrict__ g1, const float* __restrict__ be1,
    unsigned* __restrict__ h1b, int N)
{
    int t = threadIdx.x, lane = t & 63, w = t >> 6;
    int v = blockIdx.x * 4 + w;
    if (v >= N) return;
    int hsel = lane >> 4, sub = lane & 15;
    float edh = ed[(size_t)v*4 + hsel];
    float sa0 = 0.f, sa1 = 0.f, sa2 = 0.f, sp_ = 0.f;
    int beg = row_ptr[v], end = row_ptr[v+1];
    for (int j = beg + sub; j < end; j += 16){
        int s = col[j];
        float q = es[(size_t)s*4 + hsel];
        float p = __expf(lrelu(q + edh));
        const float* xp = x + (size_t)s*3;
        sp_ += p;
        sa0 += p*xp[0]; sa1 += p*xp[1]; sa2 += p*xp[2];
    }
    if (sub == 0){   // self loop, once per head
        float p = __expf(lrelu(es[(size_t)v*4 + hsel] + edh));
        const float* xp = x + (size_t)v*3;
        sp_ += p;
        sa0 += p*xp[0]; sa1 += p*xp[1]; sa2 += p*xp[2];
    }
    #pragma unroll
    for (int k = 1; k < 16; k <<= 1){
        sa0 += __shfl_xor(sa0, k); sa1 += __shfl_xor(sa1, k);
        sa2 += __shfl_xor(sa2, k); sp_ += __shfl_xor(sp_, k);
    }
    float inv = 1.f / (sp_ + 1e-16f);
    float A0 = sa0*inv, A1 = sa1*inv, A2 = sa2*inv;
    int c = lane * 2;   // channels c,c+1 ; head (c>>5) == hsel
    float h0 = A0*W1[c  ] + A1*W1[128+c  ] + A2*W1[256+c  ];
    float h1v= A0*W1[c+1] + A1*W1[128+c+1] + A2*W1[256+c+1];
    float2 bb = *(const float2*)(b1 + c);
    float oA = eluf(h0 + bb.x);
    float oB = eluf(h1v + bb.y);
    float su = oA + oB;
    #pragma unroll
    for (int k = 32; k >= 1; k >>= 1) su += __shfl_xor(su, k);
    float mean = su * (1.f/128.f);
    float aA = oA - mean, aB = oB - mean;
    float vs = aA*aA + aB*aB;
    #pragma unroll
    for (int k = 32; k >= 1; k >>= 1) vs += __shfl_xor(vs, k);
    float rstd = rsqrtf(vs * (1.f/128.f) + LN_EPS);
    float2 gg = *(const float2*)(g1 + c);
    float2 ee = *(const float2*)(be1 + c);
    float rx = aA*rstd*gg.x + ee.x, ry = aB*rstd*gg.y + ee.y;
    h1b[(size_t)v*64 + lane] = (unsigned)f2bf(rx) | ((unsigned)f2bf(ry) << 16);
}

// ---------------- layer 2 linear via MFMA: h1b[N,128]bf16 @ W2[128,64] ----------------

__global__ __launch_bounds__(256) void k_lin2(
    const unsigned short* __restrict__ h1b,   // [N][128] bf16
    const float* __restrict__ W2,             // [128][64] fp32
    const float* __restrict__ asrc, const float* __restrict__ adst,
    unsigned short* __restrict__ hlin2b, float* __restrict__ es2, float* __restrict__ ed2, int N)
{
    int t = threadIdx.x, lane = t & 63, w = t >> 6;
    int vb = blockIdx.x * 64 + w * 16;
    if (vb >= N) return;
    int lo4 = lane & 15, hi4 = lane >> 4;

    int arow = vb + lo4; if (arow >= N) arow = N - 1;
    const unsigned short* ap = h1b + (size_t)arow*128 + hi4*8;
    bf16x8 a0 = *(const bf16x8*)(ap);
    bf16x8 a1 = *(const bf16x8*)(ap + 32);
    bf16x8 a2 = *(const bf16x8*)(ap + 64);
    bf16x8 a3 = *(const bf16x8*)(ap + 96);

    f32x4 acc[4];
    #pragma unroll
    for (int nt = 0; nt < 4; ++nt) acc[nt] = (f32x4){0.f, 0.f, 0.f, 0.f};

    #pragma unroll
    for (int nt = 0; nt < 4; ++nt){
        int cb = nt*16 + lo4;
        #pragma unroll
        for (int kt = 0; kt < 4; ++kt){
            const float* wp = W2 + (size_t)(kt*32 + hi4*8)*64 + cb;
            bf16x8 b;
            #pragma unroll
            for (int j = 0; j < 8; ++j) b[j] = (short)f2bf(wp[(size_t)j*64]);
            bf16x8 a = (kt==0) ? a0 : (kt==1) ? a1 : (kt==2) ? a2 : a3;
            acc[nt] = __builtin_amdgcn_mfma_f32_16x16x32_bf16(a, b, acc[nt], 0, 0, 0);
        }
    }

    float sa0 = asrc[lo4], sa1 = asrc[16+lo4], sa2 = asrc[32+lo4], sa3 = asrc[48+lo4];
    float sb0 = adst[lo4], sb1 = adst[16+lo4], sb2 = adst[32+lo4], sb3 = adst[48+lo4];

    #pragma unroll
    for (int reg = 0; reg < 4; ++reg){
        int nr = vb + hi4*4 + reg;
        bool ok = nr < N;
        float c0 = acc[0][reg], c1 = acc[1][reg], c2 = acc[2][reg], c3 = acc[3][reg];
        if (ok){
            unsigned short* hp = hlin2b + (size_t)nr*64 + lo4;
            hp[ 0] = f2bf(c0);
            hp[16] = f2bf(c1);
            hp[32] = f2bf(c2);
            hp[48] = f2bf(c3);
        }
        float ps0 = c0*sa0 + c1*sa1, ps1 = c2*sa2 + c3*sa3;
        float pd0 = c0*sb0 + c1*sb1, pd1 = c2*sb2 + c3*sb3;
        #pragma unroll
        for (int m = 8; m >= 1; m >>= 1){
            ps0 += __shfl_xor(ps0, m); ps1 += __shfl_xor(ps1, m);
            pd0 += __shfl_xor(pd0, m); pd1 += __shfl_xor(pd1, m);
        }
        if (ok && lo4 == 0){
            float2 e; e.x = ps0; e.y = ps1;
            float2 d; d.x = pd0; d.y = pd1;
            *(float2*)(es2 + (size_t)nr*2) = e;
            *(float2*)(ed2 + (size_t)nr*2) = d;
        }
    }
}

// ---------------- layer 2: fused attn+agg, EPG=4 with 4-edge batched gathers ----------------
// lane = (slot g = lane>>4, l = lane&15); lane covers channels 4l..4l+3 (head l>>3).
// Inner loop: 4 edges per slot per iteration -> 4 independent gathers in flight.

__global__ __launch_bounds__(256) void k_agg2(
    const unsigned* __restrict__ h2b,          // [N][32] u32 = bf16[N][64]
    const float* __restrict__ es2, const float* __restrict__ ed2,
    const int* __restrict__ row_ptr, const int* __restrict__ col,
    const float* __restrict__ x, const float* __restrict__ Wskip, const float* __restrict__ bskip,
    const float* __restrict__ b2, const float* __restrict__ g2, const float* __restrict__ be2,
    float* __restrict__ h2, int N)
{
    __shared__ float sp[4][2][68];
    int t = threadIdx.x, lane = t & 63, w = t >> 6;
    int v = blockIdx.x * 4 + w;
    if (v >= N) return;
    int g = lane >> 4, l = lane & 15;
    int hsel = l >> 3;
    float2 edv = *(const float2*)(ed2 + (size_t)v*2);
    float2 esv = *(const float2*)(es2 + (size_t)v*2);
    float eh = (hsel ? esv.y : esv.x) + (hsel ? edv.y : edv.x);
    float pself = (g == 0) ? __expf(lrelu(eh)) : 0.f;
    uint2 us = *(const uint2*)(h2b + (size_t)v*32 + l*2);
    float acc[4];
    acc[0] = pself * bf_lo(us.x);
    acc[1] = pself * bf_hi(us.x);
    acc[2] = pself * bf_lo(us.y);
    acc[3] = pself * bf_hi(us.y);
    float sum_p = pself;

    int beg = row_ptr[v], end = row_ptr[v+1];
    for (int base = beg; base < end; base += 64){
        int cnt = min(64, end - base);
        int sreg = 0;
        if (lane < cnt){
            sreg = col[base + lane];
            float2 q = *(const float2*)(es2 + (size_t)sreg*2);
            sp[w][0][lane] = __expf(lrelu(q.x + edv.x));
            sp[w][1][lane] = __expf(lrelu(q.y + edv.y));
        }
        asm volatile("s_waitcnt lgkmcnt(0)" ::: "memory");
        for (int i = 0; i < cnt; i += 16){
            int e0 = i + g, e1 = e0 + 4, e2 = e0 + 8, e3 = e0 + 12;
            int s0 = __shfl(sreg, e0), s1 = __shfl(sreg, e1);
            int s2 = __shfl(sreg, e2), s3 = __shfl(sreg, e3);
            bool v0 = e0 < cnt, v1 = e1 < cnt, v2 = e2 < cnt, v3 = e3 < cnt;
            if (!v0) s0 = v;  if (!v1) s1 = v;  if (!v2) s2 = v;  if (!v3) s3 = v;
            // issue all 4 independent gathers before any use
            uint2 u0 = *(const uint2*)(h2b + (size_t)s0*32 + l*2);
            uint2 u1 = *(const uint2*)(h2b + (size_t)s1*32 + l*2);
            uint2 u2 = *(const uint2*)(h2b + (size_t)s2*32 + l*2);
            uint2 u3 = *(const uint2*)(h2b + (size_t)s3*32 + l*2);
            float p0 = v0 ? sp[w][hsel][e0] : 0.f;
            float p1 = v1 ? sp[w][hsel][e1] : 0.f;
            float p2 = v2 ? sp[w][hsel][e2] : 0.f;
            float p3 = v3 ? sp[w][hsel][e3] : 0.f;
            sum_p += (p0 + p1) + (p2 + p3);
            acc[0] += p0*bf_lo(u0.x) + p1*bf_lo(u1.x) + p2*bf_lo(u2.x) + p3*bf_lo(u3.x);
            acc[1] += p0*bf_hi(u0.x) + p1*bf_hi(u1.x) + p2*bf_hi(u2.x) + p3*bf_hi(u3.x);
            acc[2] += p0*bf_lo(u0.y) + p1*bf_lo(u1.y) + p2*bf_lo(u2.y) + p3*bf_lo(u3.y);
            acc[3] += p0*bf_hi(u0.y) + p1*bf_hi(u1.y) + p2*bf_hi(u2.y) + p3*bf_hi(u3.y);
        }
    }
    #pragma unroll
    for (int j = 0; j < 4; ++j){
        acc[j] += __shfl_xor(acc[j], 16);
        acc[j] += __shfl_xor(acc[j], 32);
    }
    sum_p += __shfl_xor(sum_p, 16);
    sum_p += __shfl_xor(sum_p, 32);
    float inv = 1.f / (sum_p + 1e-16f);
    #pragma unroll
    for (int j = 0; j < 4; ++j) acc[j] *= inv;
    // head mean: lane l pairs with l^8 (channels c and c+32)
    float xa = x[(size_t)v*3], xb = x[(size_t)v*3+1], xc = x[(size_t)v*3+2];
    int cc = (l & 7) * 4;
    float z[4];
    #pragma unroll
    for (int j = 0; j < 4; ++j){
        float other = __shfl_xor(acc[j], 8);
        float o = eluf(0.5f*(acc[j] + other) + b2[cc+j]);
        float sk = xa*Wskip[cc+j] + xb*Wskip[32+cc+j] + xc*Wskip[64+cc+j] + bskip[cc+j];
        z[j] = o + sk;
    }
    float su = z[0]+z[1]+z[2]+z[3];
    su += __shfl_xor(su,1); su += __shfl_xor(su,2); su += __shfl_xor(su,4);
    float mean = su * (1.f/32.f);
    float vs = 0.f;
    #pragma unroll
    for (int j = 0; j < 4; ++j){ float d = z[j]-mean; vs += d*d; }
    vs += __shfl_xor(vs,1); vs += __shfl_xor(vs,2); vs += __shfl_xor(vs,4);
    float rstd = rsqrtf(vs * (1.f/32.f) + LN_EPS);
    if (g == 0 && l < 8){
        float4 r;
        r.x = (z[0]-mean)*rstd*g2[cc  ] + be2[cc  ];
        r.y = (z[1]-mean)*rstd*g2[cc+1] + be2[cc+1];
        r.z = (z[2]-mean)*rstd*g2[cc+2] + be2[cc+2];
        r.w = (z[3]-mean)*rstd*g2[cc+3] + be2[cc+3];
        *(float4*)(h2 + (size_t)v*32 + cc) = r;
    }
}

// ---------------- pooling: per-graph mean/max/std (batch sorted) + projection ----------------

__global__ __launch_bounds__(256) void k_pool(
    const float* __restrict__ h2, const int* __restrict__ batch,
    const float* __restrict__ Wp, const float* __restrict__ bp,
    float* __restrict__ out, int N)
{
    int g = blockIdx.x; int t = threadIdx.x;
    __shared__ int sBeg, sEnd;
    if (t == 0){
        int lo = 0, hi = N;
        while (lo < hi){ int mid = (lo+hi) >> 1; if (batch[mid] < g) lo = mid+1; else hi = mid; }
        sBeg = lo;
        lo = sBeg; hi = N;
        while (lo < hi){ int mid = (lo+hi) >> 1; if (batch[mid] < g+1) lo = mid+1; else hi = mid; }
        sEnd = lo;
    }
    __syncthreads();
    int beg = sBeg, end = sEnd;
    int ch = t & 31, grp = t >> 5;
    float sum = 0.f, sq = 0.f, mx = -INFINITY;
    for (int i = beg + grp; i < end; i += 8){
        float val = h2[(size_t)i*32 + ch];
        sum += val; sq += val*val; mx = fmaxf(mx, val);
    }
    __shared__ float lsum[256], lsq[256], lmx[256];
    lsum[t] = sum; lsq[t] = sq; lmx[t] = mx;
    __syncthreads();
    for (int s = 4; s >= 1; s >>= 1){
        if (grp < s){
            lsum[t] += lsum[t + s*32];
            lsq [t] += lsq [t + s*32];
            lmx [t]  = fmaxf(lmx[t], lmx[t + s*32]);
        }
        __syncthreads();
    }
    __shared__ float feat[96];
    if (t < 32){
        float cnt = fmaxf((float)(end - beg), 1.f);
        float mean = lsum[t] / cnt;
        float var  = lsq[t] / cnt - mean*mean;
        feat[t]      = mean;
        feat[32 + t] = lmx[t];
        feat[64 + t] = sqrtf(fmaxf(var, 0.f));
    }
    __syncthreads();
    if (t < 48){
        float acc = bp[t];
        #pragma unroll 8
        for (int k = 0; k < 96; ++k) acc += feat[k] * Wp[k*48 + t];
        out[(size_t)g*48 + t] = acc;
    }
}

// ---------------- launcher ----------------

extern "C" void kernel_launch(void* const* d_in, const int* in_sizes, int n_in,
                              void* d_out, int out_size, void* d_ws, size_t ws_size,
                              hipStream_t stream)
{
    const float* x     = (const float*)d_in[0];
    const int*   ei    = (const int*)  d_in[1];
    const int*   batch = (const int*)  d_in[2];
    const float* W1    = (const float*)d_in[3];
    const float* as1   = (const float*)d_in[4];
    const float* ad1   = (const float*)d_in[5];
    const float* b1    = (const float*)d_in[6];
    const float* W2    = (const float*)d_in[7];
    const float* as2   = (const float*)d_in[8];
    const float* ad2   = (const float*)d_in[9];
    const float* b2    = (const float*)d_in[10];
    const float* Wskip = (const float*)d_in[11];
    const float* bskip = (const float*)d_in[12];
    const float* g1    = (const float*)d_in[13];
    const float* be1   = (const float*)d_in[14];
    const float* g2    = (const float*)d_in[15];
    const float* be2   = (const float*)d_in[16];
    const float* Wp    = (const float*)d_in[17];
    const float* bp    = (const float*)d_in[18];

    int N = in_sizes[0] / 3;
    int E = in_sizes[1] / 2;
    int B = out_size / 48;
    const int* src = ei;
    const int* dst = ei + E;
    int NBUK = (N + 63) / 64;
    int chunk = (E + NWG - 1) / NWG;
    int M = NBUK * NWG;

    char* w = (char*)d_ws;
    auto alloc = [&](size_t bytes) -> char* {
        char* p = w; w += (bytes + 255) & ~(size_t)255; return p;
    };
    int*   row_ptr = (int*)  alloc((size_t)(N+1)*4);
    int*   hist    = (int*)  alloc((size_t)M*4);
    int*   partial = (int*)  alloc(4*1024);
    int*   col     = (int*)  alloc((size_t)E*4);
    unsigned* h2b  = (unsigned*)alloc((size_t)N*32*4); // bf16[N][64] layer2 staging
    float* es      = (float*)alloc((size_t)N*4*4);
    float* ed      = (float*)alloc((size_t)N*4*4);
    unsigned* h1b  = (unsigned*)alloc((size_t)N*64*4); // bf16[N][128]
    float* h2      = (float*)alloc((size_t)N*32*4);
    unsigned* ebuf = (unsigned*)h2;                    // alias: ebuf dead before agg2 writes h2
    (void)ws_size;

    int mb  = (M + 255) / 256;
    int nb  = (N + 3) / 4;
    int nb2 = (N + 63) / 64;

    k_hist        <<<NWG, 512, 0, stream>>>(dst, hist, E, NBUK, chunk);
    k_chunk_sum   <<<mb, 256, 0, stream>>>(hist, partial, M);
    k_scan_partial<<<1, 512, 0, stream>>>(partial, mb);
    k_scan_apply  <<<mb, 256, 0, stream>>>(hist, partial, M);
    k_pscatter    <<<NWG, 512, 0, stream>>>(src, dst, hist, ebuf, E, NBUK, chunk);
    k_bfill       <<<(NBUK + 3) / 4, 256, 0, stream>>>(ebuf, hist, row_ptr, col, N, NBUK, E);

    k_lin1 <<<nb, 256, 0, stream>>>(x, W1, as1, ad1, es, ed, N);
    k_agg1 <<<nb, 256, 0, stream>>>(x, W1, es, ed, row_ptr, col, b1, g1, be1, h1b, N);
    k_lin2 <<<nb2, 256, 0, stream>>>((const unsigned short*)h1b, W2, as2, ad2,
                                     (unsigned short*)h2b, es, ed, N);
    k_agg2 <<<nb, 256, 0, stream>>>(h2b, es, ed, row_ptr, col,
                                    x, Wskip, bskip, b2, g2, be2, h2, N);
    k_pool <<<B, 256, 0, stream>>>(h2, batch, Wp, bp, (float*)d_out, N);
}

// Round 9
// 293.850 us; speedup vs baseline: 1.2122x; 1.0305x over previous
//
#include <hip/hip_runtime.h>
#include <math.h>

#define NEG_SLOPE 0.2f
#define LN_EPS 1e-5f
#define NWG 64          // scatter workgroups; hist = [NB][NWG]

typedef __attribute__((ext_vector_type(8))) short bf16x8;
typedef __attribute__((ext_vector_type(4))) float f32x4;

__device__ __forceinline__ float lrelu(float v){ return v > 0.f ? v : NEG_SLOPE * v; }
__device__ __forceinline__ float eluf (float v){ return v > 0.f ? v : expm1f(v); }

__device__ __forceinline__ unsigned short f2bf(float f){
    unsigned x = __float_as_uint(f);
    unsigned r = (x + 0x7fffu + ((x >> 16) & 1u)) >> 16;   // round-nearest-even
    return (unsigned short)r;
}
__device__ __forceinline__ float bf_lo(unsigned u){ return __uint_as_float(u << 16); }
__device__ __forceinline__ float bf_hi(unsigned u){ return __uint_as_float(u & 0xffff0000u); }

// ---------------- bucketed CSR build, atomic-free scatter ----------------

__global__ __launch_bounds__(512) void k_hist(
    const int* __restrict__ dst, int* __restrict__ hist, int E, int NB, int chunk)
{
    __shared__ int cnt[2048];
    int t = threadIdx.x, w = blockIdx.x;
    for (int i = t; i < NB; i += 512) cnt[i] = 0;
    __syncthreads();
    int e0 = w * chunk, e1 = min(E, e0 + chunk);
    for (int e = e0 + t; e < e1; e += 512)
        atomicAdd(&cnt[dst[e] >> 6], 1);
    __syncthreads();
    for (int i = t; i < NB; i += 512)
        hist[i * NWG + w] = cnt[i];
}

__global__ void k_chunk_sum(const int* __restrict__ data, int* __restrict__ partial, int M){
    __shared__ int lds[256];
    int t = threadIdx.x;
    int v = blockIdx.x * 256 + t;
    lds[t] = (v < M) ? data[v] : 0;
    __syncthreads();
    for (int s = 128; s > 0; s >>= 1){
        if (t < s) lds[t] += lds[t + s];
        __syncthreads();
    }
    if (t == 0) partial[blockIdx.x] = lds[0];
}

__global__ void k_scan_partial(int* __restrict__ partial, int n){
    __shared__ int lds[512];
    int t = threadIdx.x;
    int x = (t < n) ? partial[t] : 0;
    lds[t] = x;
    __syncthreads();
    for (int s = 1; s < 512; s <<= 1){
        int a = (t >= s) ? lds[t - s] : 0;
        __syncthreads();
        lds[t] += a;
        __syncthreads();
    }
    if (t < n) partial[t] = lds[t] - x;   // exclusive
}

__global__ void k_scan_apply(int* __restrict__ data, const int* __restrict__ partial, int M){
    __shared__ int lds[256];
    int t = threadIdx.x;
    int v = blockIdx.x * 256 + t;
    int x = (v < M) ? data[v] : 0;
    lds[t] = x;
    __syncthreads();
    for (int s = 1; s < 256; s <<= 1){
        int a = (t >= s) ? lds[t - s] : 0;
        __syncthreads();
        lds[t] += a;
        __syncthreads();
    }
    if (v < M) data[v] = partial[blockIdx.x] + lds[t] - x;   // exclusive
}

__global__ __launch_bounds__(512) void k_pscatter(
    const int* __restrict__ src, const int* __restrict__ dst,
    const int* __restrict__ shist, unsigned* __restrict__ ebuf, int E, int NB, int chunk)
{
    __shared__ int cur[2048];
    int t = threadIdx.x, w = blockIdx.x;
    for (int i = t; i < NB; i += 512) cur[i] = shist[i * NWG + w];
    __syncthreads();
    int e0 = w * chunk, e1 = min(E, e0 + chunk);
    for (int e = e0 + t; e < e1; e += 512){
        int d = dst[e];
        int pos = atomicAdd(&cur[d >> 6], 1);
        ebuf[pos] = ((unsigned)(d & 63) << 26) | (unsigned)src[e];
    }
}

// one wave per bucket: local degree count -> wave-scan -> row_ptr + LDS-cursor fill
__global__ __launch_bounds__(256) void k_bfill(
    const unsigned* __restrict__ ebuf, const int* __restrict__ shist,
    int* __restrict__ row_ptr, int* __restrict__ col, int N, int NB, int E)
{
    __shared__ int scnt[4][64];
    int t = threadIdx.x, lane = t & 63, w = t >> 6;
    int b = blockIdx.x * 4 + w;
    bool act = b < NB;
    if (t == 0 && blockIdx.x == 0) row_ptr[N] = E;
    scnt[w][lane] = 0;
    __syncthreads();
    int ebeg = 0, eend = 0;
    if (act){
        ebeg = shist[b * NWG];
        eend = (b + 1 < NB) ? shist[(b + 1) * NWG] : E;
    }
    for (int j = ebeg + lane; j < eend; j += 64)
        atomicAdd(&scnt[w][ebuf[j] >> 26], 1);
    __syncthreads();
    int deg = scnt[w][lane];
    int incl = deg;
    #pragma unroll
    for (int k = 1; k < 64; k <<= 1){
        int up = __shfl_up(incl, k);
        if (lane >= k) incl += up;
    }
    int excl = incl - deg;
    int base = act ? ebeg : 0;
    int v = b * 64 + lane;
    if (act && v < N) row_ptr[v] = base + excl;
    __syncthreads();
    scnt[w][lane] = base + excl;
    __syncthreads();
    for (int j = ebeg + lane; j < eend; j += 64){
        unsigned u = ebuf[j];
        int pos = atomicAdd(&scnt[w][u >> 26], 1);
        col[pos] = (int)(u & 0x03FFFFFFu);
    }
}

// ---------------- layer 1 attention logits: es/ed only ----------------

__global__ __launch_bounds__(256) void k_lin1(
    const float* __restrict__ x, const float* __restrict__ W1,
    const float* __restrict__ asrc, const float* __restrict__ adst,
    float* __restrict__ es, float* __restrict__ ed, int N)
{
    __shared__ float sW[384], sA[128], sB[128];
    int t = threadIdx.x;
    for (int i = t; i < 384; i += 256) sW[i] = W1[i];
    for (int i = t; i < 128; i += 256){ sA[i] = asrc[i]; sB[i] = adst[i]; }
    __syncthreads();
    int lane = t & 63;
    int v = blockIdx.x * 4 + (t >> 6);
    if (v >= N) return;
    float x0 = x[(size_t)v*3], x1 = x[(size_t)v*3+1], x2 = x[(size_t)v*3+2];
    int c = lane * 2;
    float h0 = x0*sW[c  ] + x1*sW[128+c  ] + x2*sW[256+c  ];
    float h1 = x0*sW[c+1] + x1*sW[128+c+1] + x2*sW[256+c+1];
    int hsel = lane >> 4;
    float ts = h0*sA[c] + h1*sA[c+1];
    float td = h0*sB[c] + h1*sB[c+1];
    #pragma unroll
    for (int m = 8; m >= 1; m >>= 1){
        ts += __shfl_xor(ts, m); td += __shfl_xor(td, m);
    }
    if ((lane & 15) == 0){
        es[(size_t)v*4 + hsel] = ts;
        ed[(size_t)v*4 + hsel] = td;
    }
}

// ---------------- layer 1: factored attn+agg, 2-deep pipelined gathers ----------------
// sum_e p_e*(x[s]@W) = (sum_e p_e*x[s])@W : aggregate weighted 3-vector per head.

__global__ __launch_bounds__(256) void k_agg1(
    const float* __restrict__ x, const float* __restrict__ W1,
    const float* __restrict__ es, const float* __restrict__ ed,
    const int* __restrict__ row_ptr, const int* __restrict__ col,
    const float* __restrict__ b1, const float* __restrict__ g1, const float* __restrict__ be1,
    unsigned* __restrict__ h1b, int N)
{
    int t = threadIdx.x, lane = t & 63, w = t >> 6;
    int v = blockIdx.x * 4 + w;
    if (v >= N) return;
    int hsel = lane >> 4, sub = lane & 15;
    float edh = ed[(size_t)v*4 + hsel];
    float sa0 = 0.f, sa1 = 0.f, sa2 = 0.f, sp_ = 0.f;
    int beg = row_ptr[v], end = row_ptr[v+1];
    int j = beg + sub;
    for (; j + 16 < end; j += 32){
        int sA = col[j], sB = col[j + 16];
        float qA = es[(size_t)sA*4 + hsel];
        float qB = es[(size_t)sB*4 + hsel];
        const float* xA = x + (size_t)sA*3;
        const float* xB = x + (size_t)sB*3;
        float a0 = xA[0], a1 = xA[1], a2 = xA[2];
        float b0 = xB[0], b1v = xB[1], b2v = xB[2];
        float pA = __expf(lrelu(qA + edh));
        float pB = __expf(lrelu(qB + edh));
        sp_ += pA + pB;
        sa0 += pA*a0 + pB*b0;
        sa1 += pA*a1 + pB*b1v;
        sa2 += pA*a2 + pB*b2v;
    }
    if (j < end){
        int s = col[j];
        float q = es[(size_t)s*4 + hsel];
        float p = __expf(lrelu(q + edh));
        const float* xp = x + (size_t)s*3;
        sp_ += p;
        sa0 += p*xp[0]; sa1 += p*xp[1]; sa2 += p*xp[2];
    }
    if (sub == 0){   // self loop, once per head
        float p = __expf(lrelu(es[(size_t)v*4 + hsel] + edh));
        const float* xp = x + (size_t)v*3;
        sp_ += p;
        sa0 += p*xp[0]; sa1 += p*xp[1]; sa2 += p*xp[2];
    }
    #pragma unroll
    for (int k = 1; k < 16; k <<= 1){
        sa0 += __shfl_xor(sa0, k); sa1 += __shfl_xor(sa1, k);
        sa2 += __shfl_xor(sa2, k); sp_ += __shfl_xor(sp_, k);
    }
    float inv = 1.f / (sp_ + 1e-16f);
    float A0 = sa0*inv, A1 = sa1*inv, A2 = sa2*inv;
    int c = lane * 2;   // channels c,c+1 ; head (c>>5) == hsel
    float h0 = A0*W1[c  ] + A1*W1[128+c  ] + A2*W1[256+c  ];
    float h1v= A0*W1[c+1] + A1*W1[128+c+1] + A2*W1[256+c+1];
    float2 bb = *(const float2*)(b1 + c);
    float oA = eluf(h0 + bb.x);
    float oB = eluf(h1v + bb.y);
    float su = oA + oB;
    #pragma unroll
    for (int k = 32; k >= 1; k >>= 1) su += __shfl_xor(su, k);
    float mean = su * (1.f/128.f);
    float aA = oA - mean, aB = oB - mean;
    float vs = aA*aA + aB*aB;
    #pragma unroll
    for (int k = 32; k >= 1; k >>= 1) vs += __shfl_xor(vs, k);
    float rstd = rsqrtf(vs * (1.f/128.f) + LN_EPS);
    float2 gg = *(const float2*)(g1 + c);
    float2 ee = *(const float2*)(be1 + c);
    float rx = aA*rstd*gg.x + ee.x, ry = aB*rstd*gg.y + ee.y;
    h1b[(size_t)v*64 + lane] = (unsigned)f2bf(rx) | ((unsigned)f2bf(ry) << 16);
}

// ---------------- layer 2 linear via MFMA: h1b[N,128]bf16 @ W2[128,64] ----------------

__global__ __launch_bounds__(256) void k_lin2(
    const unsigned short* __restrict__ h1b,   // [N][128] bf16
    const float* __restrict__ W2,             // [128][64] fp32
    const float* __restrict__ asrc, const float* __restrict__ adst,
    unsigned short* __restrict__ hlin2b, float* __restrict__ es2, float* __restrict__ ed2, int N)
{
    int t = threadIdx.x, lane = t & 63, w = t >> 6;
    int vb = blockIdx.x * 64 + w * 16;
    if (vb >= N) return;
    int lo4 = lane & 15, hi4 = lane >> 4;

    int arow = vb + lo4; if (arow >= N) arow = N - 1;
    const unsigned short* ap = h1b + (size_t)arow*128 + hi4*8;
    bf16x8 a0 = *(const bf16x8*)(ap);
    bf16x8 a1 = *(const bf16x8*)(ap + 32);
    bf16x8 a2 = *(const bf16x8*)(ap + 64);
    bf16x8 a3 = *(const bf16x8*)(ap + 96);

    f32x4 acc[4];
    #pragma unroll
    for (int nt = 0; nt < 4; ++nt) acc[nt] = (f32x4){0.f, 0.f, 0.f, 0.f};

    #pragma unroll
    for (int nt = 0; nt < 4; ++nt){
        int cb = nt*16 + lo4;
        #pragma unroll
        for (int kt = 0; kt < 4; ++kt){
            const float* wp = W2 + (size_t)(kt*32 + hi4*8)*64 + cb;
            bf16x8 b;
            #pragma unroll
            for (int j = 0; j < 8; ++j) b[j] = (short)f2bf(wp[(size_t)j*64]);
            bf16x8 a = (kt==0) ? a0 : (kt==1) ? a1 : (kt==2) ? a2 : a3;
            acc[nt] = __builtin_amdgcn_mfma_f32_16x16x32_bf16(a, b, acc[nt], 0, 0, 0);
        }
    }

    float sa0 = asrc[lo4], sa1 = asrc[16+lo4], sa2 = asrc[32+lo4], sa3 = asrc[48+lo4];
    float sb0 = adst[lo4], sb1 = adst[16+lo4], sb2 = adst[32+lo4], sb3 = adst[48+lo4];

    #pragma unroll
    for (int reg = 0; reg < 4; ++reg){
        int nr = vb + hi4*4 + reg;
        bool ok = nr < N;
        float c0 = acc[0][reg], c1 = acc[1][reg], c2 = acc[2][reg], c3 = acc[3][reg];
        if (ok){
            unsigned short* hp = hlin2b + (size_t)nr*64 + lo4;
            hp[ 0] = f2bf(c0);
            hp[16] = f2bf(c1);
            hp[32] = f2bf(c2);
            hp[48] = f2bf(c3);
        }
        float ps0 = c0*sa0 + c1*sa1, ps1 = c2*sa2 + c3*sa3;
        float pd0 = c0*sb0 + c1*sb1, pd1 = c2*sb2 + c3*sb3;
        #pragma unroll
        for (int m = 8; m >= 1; m >>= 1){
            ps0 += __shfl_xor(ps0, m); ps1 += __shfl_xor(ps1, m);
            pd0 += __shfl_xor(pd0, m); pd1 += __shfl_xor(pd1, m);
        }
        if (ok && lo4 == 0){
            float2 e; e.x = ps0; e.y = ps1;
            float2 d; d.x = pd0; d.y = pd1;
            *(float2*)(es2 + (size_t)nr*2) = e;
            *(float2*)(ed2 + (size_t)nr*2) = d;
        }
    }
}

// ---------------- layer 2: fused attn+agg, EPG=4 with 8-deep batched gathers ----------------
// lane = (slot g = lane>>4, l = lane&15); lane covers channels 4l..4l+3 (head l>>3).
// Inner loop: 8 edges per slot per iteration -> 8 independent gathers in flight.

__global__ __launch_bounds__(256) void k_agg2(
    const unsigned* __restrict__ h2b,          // [N][32] u32 = bf16[N][64]
    const float* __restrict__ es2, const float* __restrict__ ed2,
    const int* __restrict__ row_ptr, const int* __restrict__ col,
    const float* __restrict__ x, const float* __restrict__ Wskip, const float* __restrict__ bskip,
    const float* __restrict__ b2, const float* __restrict__ g2, const float* __restrict__ be2,
    float* __restrict__ h2, int N)
{
    __shared__ float sp[4][2][68];
    int t = threadIdx.x, lane = t & 63, w = t >> 6;
    int v = blockIdx.x * 4 + w;
    if (v >= N) return;
    int g = lane >> 4, l = lane & 15;
    int hsel = l >> 3;
    float2 edv = *(const float2*)(ed2 + (size_t)v*2);
    float2 esv = *(const float2*)(es2 + (size_t)v*2);
    float eh = (hsel ? esv.y : esv.x) + (hsel ? edv.y : edv.x);
    float pself = (g == 0) ? __expf(lrelu(eh)) : 0.f;
    uint2 us = *(const uint2*)(h2b + (size_t)v*32 + l*2);
    float acc[4];
    acc[0] = pself * bf_lo(us.x);
    acc[1] = pself * bf_hi(us.x);
    acc[2] = pself * bf_lo(us.y);
    acc[3] = pself * bf_hi(us.y);
    float sum_p = pself;

    int beg = row_ptr[v], end = row_ptr[v+1];
    for (int base = beg; base < end; base += 64){
        int cnt = min(64, end - base);
        int sreg = 0;
        if (lane < cnt){
            sreg = col[base + lane];
            float2 q = *(const float2*)(es2 + (size_t)sreg*2);
            sp[w][0][lane] = __expf(lrelu(q.x + edv.x));
            sp[w][1][lane] = __expf(lrelu(q.y + edv.y));
        }
        asm volatile("s_waitcnt lgkmcnt(0)" ::: "memory");
        for (int i = 0; i < cnt; i += 32){
            int e0 = i + g;
            int s0 = __shfl(sreg, e0),      s1 = __shfl(sreg, e0 + 4);
            int s2 = __shfl(sreg, e0 + 8),  s3 = __shfl(sreg, e0 + 12);
            int s4 = __shfl(sreg, e0 + 16), s5 = __shfl(sreg, e0 + 20);
            int s6 = __shfl(sreg, e0 + 24), s7 = __shfl(sreg, e0 + 28);
            bool v0 = e0      < cnt, v1 = e0 + 4  < cnt, v2 = e0 + 8  < cnt, v3 = e0 + 12 < cnt;
            bool v4 = e0 + 16 < cnt, v5 = e0 + 20 < cnt, v6 = e0 + 24 < cnt, v7 = e0 + 28 < cnt;
            if (!v0) s0 = v;  if (!v1) s1 = v;  if (!v2) s2 = v;  if (!v3) s3 = v;
            if (!v4) s4 = v;  if (!v5) s5 = v;  if (!v6) s6 = v;  if (!v7) s7 = v;
            // issue all 8 independent gathers before any use
            uint2 u0 = *(const uint2*)(h2b + (size_t)s0*32 + l*2);
            uint2 u1 = *(const uint2*)(h2b + (size_t)s1*32 + l*2);
            uint2 u2 = *(const uint2*)(h2b + (size_t)s2*32 + l*2);
            uint2 u3 = *(const uint2*)(h2b + (size_t)s3*32 + l*2);
            uint2 u4 = *(const uint2*)(h2b + (size_t)s4*32 + l*2);
            uint2 u5 = *(const uint2*)(h2b + (size_t)s5*32 + l*2);
            uint2 u6 = *(const uint2*)(h2b + (size_t)s6*32 + l*2);
            uint2 u7 = *(const uint2*)(h2b + (size_t)s7*32 + l*2);
            float p0 = v0 ? sp[w][hsel][e0     ] : 0.f;
            float p1 = v1 ? sp[w][hsel][e0 +  4] : 0.f;
            float p2 = v2 ? sp[w][hsel][e0 +  8] : 0.f;
            float p3 = v3 ? sp[w][hsel][e0 + 12] : 0.f;
            float p4 = v4 ? sp[w][hsel][e0 + 16] : 0.f;
            float p5 = v5 ? sp[w][hsel][e0 + 20] : 0.f;
            float p6 = v6 ? sp[w][hsel][e0 + 24] : 0.f;
            float p7 = v7 ? sp[w][hsel][e0 + 28] : 0.f;
            sum_p += ((p0 + p1) + (p2 + p3)) + ((p4 + p5) + (p6 + p7));
            acc[0] += p0*bf_lo(u0.x) + p1*bf_lo(u1.x) + p2*bf_lo(u2.x) + p3*bf_lo(u3.x)
                    + p4*bf_lo(u4.x) + p5*bf_lo(u5.x) + p6*bf_lo(u6.x) + p7*bf_lo(u7.x);
            acc[1] += p0*bf_hi(u0.x) + p1*bf_hi(u1.x) + p2*bf_hi(u2.x) + p3*bf_hi(u3.x)
                    + p4*bf_hi(u4.x) + p5*bf_hi(u5.x) + p6*bf_hi(u6.x) + p7*bf_hi(u7.x);
            acc[2] += p0*bf_lo(u0.y) + p1*bf_lo(u1.y) + p2*bf_lo(u2.y) + p3*bf_lo(u3.y)
                    + p4*bf_lo(u4.y) + p5*bf_lo(u5.y) + p6*bf_lo(u6.y) + p7*bf_lo(u7.y);
            acc[3] += p0*bf_hi(u0.y) + p1*bf_hi(u1.y) + p2*bf_hi(u2.y) + p3*bf_hi(u3.y)
                    + p4*bf_hi(u4.y) + p5*bf_hi(u5.y) + p6*bf_hi(u6.y) + p7*bf_hi(u7.y);
        }
    }
    #pragma unroll
    for (int j = 0; j < 4; ++j){
        acc[j] += __shfl_xor(acc[j], 16);
        acc[j] += __shfl_xor(acc[j], 32);
    }
    sum_p += __shfl_xor(sum_p, 16);
    sum_p += __shfl_xor(sum_p, 32);
    float inv = 1.f / (sum_p + 1e-16f);
    #pragma unroll
    for (int j = 0; j < 4; ++j) acc[j] *= inv;
    // head mean: lane l pairs with l^8 (channels c and c+32)
    float xa = x[(size_t)v*3], xb = x[(size_t)v*3+1], xc = x[(size_t)v*3+2];
    int cc = (l & 7) * 4;
    float z[4];
    #pragma unroll
    for (int j = 0; j < 4; ++j){
        float other = __shfl_xor(acc[j], 8);
        float o = eluf(0.5f*(acc[j] + other) + b2[cc+j]);
        float sk = xa*Wskip[cc+j] + xb*Wskip[32+cc+j] + xc*Wskip[64+cc+j] + bskip[cc+j];
        z[j] = o + sk;
    }
    float su = z[0]+z[1]+z[2]+z[3];
    su += __shfl_xor(su,1); su += __shfl_xor(su,2); su += __shfl_xor(su,4);
    float mean = su * (1.f/32.f);
    float vs = 0.f;
    #pragma unroll
    for (int j = 0; j < 4; ++j){ float d = z[j]-mean; vs += d*d; }
    vs += __shfl_xor(vs,1); vs += __shfl_xor(vs,2); vs += __shfl_xor(vs,4);
    float rstd = rsqrtf(vs * (1.f/32.f) + LN_EPS);
    if (g == 0 && l < 8){
        float4 r;
        r.x = (z[0]-mean)*rstd*g2[cc  ] + be2[cc  ];
        r.y = (z[1]-mean)*rstd*g2[cc+1] + be2[cc+1];
        r.z = (z[2]-mean)*rstd*g2[cc+2] + be2[cc+2];
        r.w = (z[3]-mean)*rstd*g2[cc+3] + be2[cc+3];
        *(float4*)(h2 + (size_t)v*32 + cc) = r;
    }
}

// ---------------- pooling: per-graph mean/max/std (batch sorted) + projection ----------------

__global__ __launch_bounds__(256) void k_pool(
    const float* __restrict__ h2, const int* __restrict__ batch,
    const float* __restrict__ Wp, const float* __restrict__ bp,
    float* __restrict__ out, int N)
{
    int g = blockIdx.x; int t = threadIdx.x;
    __shared__ int sBeg, sEnd;
    if (t == 0){
        int lo = 0, hi = N;
        while (lo < hi){ int mid = (lo+hi) >> 1; if (batch[mid] < g) lo = mid+1; else hi = mid; }
        sBeg = lo;
        lo = sBeg; hi = N;
        while (lo < hi){ int mid = (lo+hi) >> 1; if (batch[mid] < g+1) lo = mid+1; else hi = mid; }
        sEnd = lo;
    }
    __syncthreads();
    int beg = sBeg, end = sEnd;
    int ch = t & 31, grp = t >> 5;
    float sum = 0.f, sq = 0.f, mx = -INFINITY;
    for (int i = beg + grp; i < end; i += 8){
        float val = h2[(size_t)i*32 + ch];
        sum += val; sq += val*val; mx = fmaxf(mx, val);
    }
    __shared__ float lsum[256], lsq[256], lmx[256];
    lsum[t] = sum; lsq[t] = sq; lmx[t] = mx;
    __syncthreads();
    for (int s = 4; s >= 1; s >>= 1){
        if (grp < s){
            lsum[t] += lsum[t + s*32];
            lsq [t] += lsq [t + s*32];
            lmx [t]  = fmaxf(lmx[t], lmx[t + s*32]);
        }
        __syncthreads();
    }
    __shared__ float feat[96];
    if (t < 32){
        float cnt = fmaxf((float)(end - beg), 1.f);
        float mean = lsum[t] / cnt;
        float var  = lsq[t] / cnt - mean*mean;
        feat[t]      = mean;
        feat[32 + t] = lmx[t];
        feat[64 + t] = sqrtf(fmaxf(var, 0.f));
    }
    __syncthreads();
    if (t < 48){
        float acc = bp[t];
        #pragma unroll 8
        for (int k = 0; k < 96; ++k) acc += feat[k] * Wp[k*48 + t];
        out[(size_t)g*48 + t] = acc;
    }
}

// ---------------- launcher ----------------

extern "C" void kernel_launch(void* const* d_in, const int* in_sizes, int n_in,
                              void* d_out, int out_size, void* d_ws, size_t ws_size,
                              hipStream_t stream)
{
    const float* x     = (const float*)d_in[0];
    const int*   ei    = (const int*)  d_in[1];
    const int*   batch = (const int*)  d_in[2];
    const float* W1    = (const float*)d_in[3];
    const float* as1   = (const float*)d_in[4];
    const float* ad1   = (const float*)d_in[5];
    const float* b1    = (const float*)d_in[6];
    const float* W2    = (const float*)d_in[7];
    const float* as2   = (const float*)d_in[8];
    const float* ad2   = (const float*)d_in[9];
    const float* b2    = (const float*)d_in[10];
    const float* Wskip = (const float*)d_in[11];
    const float* bskip = (const float*)d_in[12];
    const float* g1    = (const float*)d_in[13];
    const float* be1   = (const float*)d_in[14];
    const float* g2    = (const float*)d_in[15];
    const float* be2   = (const float*)d_in[16];
    const float* Wp    = (const float*)d_in[17];
    const float* bp    = (const float*)d_in[18];

    int N = in_sizes[0] / 3;
    int E = in_sizes[1] / 2;
    int B = out_size / 48;
    const int* src = ei;
    const int* dst = ei + E;
    int NBUK = (N + 63) / 64;
    int chunk = (E + NWG - 1) / NWG;
    int M = NBUK * NWG;                    // 100032 -> mb=391 <= 512 ok

    char* w = (char*)d_ws;
    auto alloc = [&](size_t bytes) -> char* {
        char* p = w; w += (bytes + 255) & ~(size_t)255; return p;
    };
    int*   row_ptr = (int*)  alloc((size_t)(N+1)*4);
    int*   hist    = (int*)  alloc((size_t)M*4);
    int*   partial = (int*)  alloc(4*1024);
    int*   col     = (int*)  alloc((size_t)E*4);
    unsigned* h2b  = (unsigned*)alloc((size_t)N*32*4); // bf16[N][64] layer2 staging
    float* es      = (float*)alloc((size_t)N*4*4);
    float* ed      = (float*)alloc((size_t)N*4*4);
    unsigned* h1b  = (unsigned*)alloc((size_t)N*64*4); // bf16[N][128]
    float* h2      = (float*)alloc((size_t)N*32*4);
    unsigned* ebuf = (unsigned*)h2;                    // alias: ebuf dead before agg2 writes h2
    (void)ws_size;

    int mb  = (M + 255) / 256;
    int nb  = (N + 3) / 4;
    int nb2 = (N + 63) / 64;

    k_hist        <<<NWG, 512, 0, stream>>>(dst, hist, E, NBUK, chunk);
    k_chunk_sum   <<<mb, 256, 0, stream>>>(hist, partial, M);
    k_scan_partial<<<1, 512, 0, stream>>>(partial, mb);
    k_scan_apply  <<<mb, 256, 0, stream>>>(hist, partial, M);
    k_pscatter    <<<NWG, 512, 0, stream>>>(src, dst, hist, ebuf, E, NBUK, chunk);
    k_bfill       <<<(NBUK + 3) / 4, 256, 0, stream>>>(ebuf, hist, row_ptr, col, N, NBUK, E);

    k_lin1 <<<nb, 256, 0, stream>>>(x, W1, as1, ad1, es, ed, N);
    k_agg1 <<<nb, 256, 0, stream>>>(x, W1, es, ed, row_ptr, col, b1, g1, be1, h1b, N);
    k_lin2 <<<nb2, 256, 0, stream>>>((const unsigned short*)h1b, W2, as2, ad2,
                                     (unsigned short*)h2b, es, ed, N);
    k_agg2 <<<nb, 256, 0, stream>>>(h2b, es, ed, row_ptr, col,
                                    x, Wskip, bskip, b2, g2, be2, h2, N);
    k_pool <<<B, 256, 0, stream>>>(h2, batch, Wp, bp, (float*)d_out, N);
}

// Round 10
// 292.738 us; speedup vs baseline: 1.2168x; 1.0038x over previous
//
#include <hip/hip_runtime.h>
#include <math.h>

#define NEG_SLOPE 0.2f
#define LN_EPS 1e-5f
#define NWG 64          // scatter workgroups; hist = [NB][NWG]

typedef __attribute__((ext_vector_type(8))) short bf16x8;
typedef __attribute__((ext_vector_type(4))) float f32x4;

__device__ __forceinline__ float lrelu(float v){ return v > 0.f ? v : NEG_SLOPE * v; }
__device__ __forceinline__ float eluf (float v){ return v > 0.f ? v : expm1f(v); }

__device__ __forceinline__ unsigned short f2bf(float f){
    unsigned x = __float_as_uint(f);
    unsigned r = (x + 0x7fffu + ((x >> 16) & 1u)) >> 16;   // round-nearest-even
    return (unsigned short)r;
}
__device__ __forceinline__ float bf_lo(unsigned u){ return __uint_as_float(u << 16); }
__device__ __forceinline__ float bf_hi(unsigned u){ return __uint_as_float(u & 0xffff0000u); }

// ---------------- pad x[N,3] -> x4[N] (16B aligned rows: 1 gather transaction) ----------------

__global__ void k_padx(const float* __restrict__ x, float4* __restrict__ x4, int N){
    int v = blockIdx.x * 256 + threadIdx.x;
    if (v < N){
        float4 r;
        r.x = x[(size_t)v*3]; r.y = x[(size_t)v*3+1]; r.z = x[(size_t)v*3+2]; r.w = 0.f;
        x4[v] = r;
    }
}

// ---------------- bucketed CSR build, atomic-free scatter ----------------

__global__ __launch_bounds__(512) void k_hist(
    const int* __restrict__ dst, int* __restrict__ hist, int E, int NB, int chunk)
{
    __shared__ int cnt[2048];
    int t = threadIdx.x, w = blockIdx.x;
    for (int i = t; i < NB; i += 512) cnt[i] = 0;
    __syncthreads();
    int e0 = w * chunk, e1 = min(E, e0 + chunk);
    for (int e = e0 + t; e < e1; e += 512)
        atomicAdd(&cnt[dst[e] >> 6], 1);
    __syncthreads();
    for (int i = t; i < NB; i += 512)
        hist[i * NWG + w] = cnt[i];
}

__global__ void k_chunk_sum(const int* __restrict__ data, int* __restrict__ partial, int M){
    __shared__ int lds[256];
    int t = threadIdx.x;
    int v = blockIdx.x * 256 + t;
    lds[t] = (v < M) ? data[v] : 0;
    __syncthreads();
    for (int s = 128; s > 0; s >>= 1){
        if (t < s) lds[t] += lds[t + s];
        __syncthreads();
    }
    if (t == 0) partial[blockIdx.x] = lds[0];
}

__global__ void k_scan_partial(int* __restrict__ partial, int n){
    __shared__ int lds[512];
    int t = threadIdx.x;
    int x = (t < n) ? partial[t] : 0;
    lds[t] = x;
    __syncthreads();
    for (int s = 1; s < 512; s <<= 1){
        int a = (t >= s) ? lds[t - s] : 0;
        __syncthreads();
        lds[t] += a;
        __syncthreads();
    }
    if (t < n) partial[t] = lds[t] - x;   // exclusive
}

__global__ void k_scan_apply(int* __restrict__ data, const int* __restrict__ partial, int M){
    __shared__ int lds[256];
    int t = threadIdx.x;
    int v = blockIdx.x * 256 + t;
    int x = (v < M) ? data[v] : 0;
    lds[t] = x;
    __syncthreads();
    for (int s = 1; s < 256; s <<= 1){
        int a = (t >= s) ? lds[t - s] : 0;
        __syncthreads();
        lds[t] += a;
        __syncthreads();
    }
    if (v < M) data[v] = partial[blockIdx.x] + lds[t] - x;   // exclusive
}

__global__ __launch_bounds__(512) void k_pscatter(
    const int* __restrict__ src, const int* __restrict__ dst,
    const int* __restrict__ shist, unsigned* __restrict__ ebuf, int E, int NB, int chunk)
{
    __shared__ int cur[2048];
    int t = threadIdx.x, w = blockIdx.x;
    for (int i = t; i < NB; i += 512) cur[i] = shist[i * NWG + w];
    __syncthreads();
    int e0 = w * chunk, e1 = min(E, e0 + chunk);
    for (int e = e0 + t; e < e1; e += 512){
        int d = dst[e];
        int pos = atomicAdd(&cur[d >> 6], 1);
        ebuf[pos] = ((unsigned)(d & 63) << 26) | (unsigned)src[e];
    }
}

// one wave per bucket: local degree count -> wave-scan -> row_ptr + LDS-cursor fill
__global__ __launch_bounds__(256) void k_bfill(
    const unsigned* __restrict__ ebuf, const int* __restrict__ shist,
    int* __restrict__ row_ptr, int* __restrict__ col, int N, int NB, int E)
{
    __shared__ int scnt[4][64];
    int t = threadIdx.x, lane = t & 63, w = t >> 6;
    int b = blockIdx.x * 4 + w;
    bool act = b < NB;
    if (t == 0 && blockIdx.x == 0) row_ptr[N] = E;
    scnt[w][lane] = 0;
    __syncthreads();
    int ebeg = 0, eend = 0;
    if (act){
        ebeg = shist[b * NWG];
        eend = (b + 1 < NB) ? shist[(b + 1) * NWG] : E;
    }
    for (int j = ebeg + lane; j < eend; j += 64)
        atomicAdd(&scnt[w][ebuf[j] >> 26], 1);
    __syncthreads();
    int deg = scnt[w][lane];
    int incl = deg;
    #pragma unroll
    for (int k = 1; k < 64; k <<= 1){
        int up = __shfl_up(incl, k);
        if (lane >= k) incl += up;
    }
    int excl = incl - deg;
    int base = act ? ebeg : 0;
    int v = b * 64 + lane;
    if (act && v < N) row_ptr[v] = base + excl;
    __syncthreads();
    scnt[w][lane] = base + excl;
    __syncthreads();
    for (int j = ebeg + lane; j < eend; j += 64){
        unsigned u = ebuf[j];
        int pos = atomicAdd(&scnt[w][u >> 26], 1);
        col[pos] = (int)(u & 0x03FFFFFFu);
    }
}

// ---------------- layer 1 attention logits: es/ed only ----------------

__global__ __launch_bounds__(256) void k_lin1(
    const float4* __restrict__ x4, const float* __restrict__ W1,
    const float* __restrict__ asrc, const float* __restrict__ adst,
    float* __restrict__ es, float* __restrict__ ed, int N)
{
    __shared__ float sW[384], sA[128], sB[128];
    int t = threadIdx.x;
    for (int i = t; i < 384; i += 256) sW[i] = W1[i];
    for (int i = t; i < 128; i += 256){ sA[i] = asrc[i]; sB[i] = adst[i]; }
    __syncthreads();
    int lane = t & 63;
    int v = blockIdx.x * 4 + (t >> 6);
    if (v >= N) return;
    float4 xv = x4[v];
    float x0 = xv.x, x1 = xv.y, x2 = xv.z;
    int c = lane * 2;
    float h0 = x0*sW[c  ] + x1*sW[128+c  ] + x2*sW[256+c  ];
    float h1 = x0*sW[c+1] + x1*sW[128+c+1] + x2*sW[256+c+1];
    int hsel = lane >> 4;
    float ts = h0*sA[c] + h1*sA[c+1];
    float td = h0*sB[c] + h1*sB[c+1];
    #pragma unroll
    for (int m = 8; m >= 1; m >>= 1){
        ts += __shfl_xor(ts, m); td += __shfl_xor(td, m);
    }
    if ((lane & 15) == 0){
        es[(size_t)v*4 + hsel] = ts;
        ed[(size_t)v*4 + hsel] = td;
    }
}

// ---------------- layer 1: factored attn+agg, 2-deep pipelined gathers, float4 x ----------------
// sum_e p_e*(x[s]@W) = (sum_e p_e*x[s])@W : aggregate weighted 3-vector per head.

__global__ __launch_bounds__(256) void k_agg1(
    const float4* __restrict__ x4, const float* __restrict__ W1,
    const float* __restrict__ es, const float* __restrict__ ed,
    const int* __restrict__ row_ptr, const int* __restrict__ col,
    const float* __restrict__ b1, const float* __restrict__ g1, const float* __restrict__ be1,
    unsigned* __restrict__ h1b, int N)
{
    int t = threadIdx.x, lane = t & 63, w = t >> 6;
    int v = blockIdx.x * 4 + w;
    if (v >= N) return;
    int hsel = lane >> 4, sub = lane & 15;
    float edh = ed[(size_t)v*4 + hsel];
    float sa0 = 0.f, sa1 = 0.f, sa2 = 0.f, sp_ = 0.f;
    int beg = row_ptr[v], end = row_ptr[v+1];
    int j = beg + sub;
    for (; j + 16 < end; j += 32){
        int sA = col[j], sB = col[j + 16];
        float qA = es[(size_t)sA*4 + hsel];
        float qB = es[(size_t)sB*4 + hsel];
        float4 a = x4[sA];
        float4 b = x4[sB];
        float pA = __expf(lrelu(qA + edh));
        float pB = __expf(lrelu(qB + edh));
        sp_ += pA + pB;
        sa0 += pA*a.x + pB*b.x;
        sa1 += pA*a.y + pB*b.y;
        sa2 += pA*a.z + pB*b.z;
    }
    if (j < end){
        int s = col[j];
        float q = es[(size_t)s*4 + hsel];
        float p = __expf(lrelu(q + edh));
        float4 a = x4[s];
        sp_ += p;
        sa0 += p*a.x; sa1 += p*a.y; sa2 += p*a.z;
    }
    if (sub == 0){   // self loop, once per head
        float p = __expf(lrelu(es[(size_t)v*4 + hsel] + edh));
        float4 a = x4[v];
        sp_ += p;
        sa0 += p*a.x; sa1 += p*a.y; sa2 += p*a.z;
    }
    #pragma unroll
    for (int k = 1; k < 16; k <<= 1){
        sa0 += __shfl_xor(sa0, k); sa1 += __shfl_xor(sa1, k);
        sa2 += __shfl_xor(sa2, k); sp_ += __shfl_xor(sp_, k);
    }
    float inv = 1.f / (sp_ + 1e-16f);
    float A0 = sa0*inv, A1 = sa1*inv, A2 = sa2*inv;
    int c = lane * 2;   // channels c,c+1 ; head (c>>5) == hsel
    float h0 = A0*W1[c  ] + A1*W1[128+c  ] + A2*W1[256+c  ];
    float h1v= A0*W1[c+1] + A1*W1[128+c+1] + A2*W1[256+c+1];
    float2 bb = *(const float2*)(b1 + c);
    float oA = eluf(h0 + bb.x);
    float oB = eluf(h1v + bb.y);
    float su = oA + oB;
    #pragma unroll
    for (int k = 32; k >= 1; k >>= 1) su += __shfl_xor(su, k);
    float mean = su * (1.f/128.f);
    float aA = oA - mean, aB = oB - mean;
    float vs = aA*aA + aB*aB;
    #pragma unroll
    for (int k = 32; k >= 1; k >>= 1) vs += __shfl_xor(vs, k);
    float rstd = rsqrtf(vs * (1.f/128.f) + LN_EPS);
    float2 gg = *(const float2*)(g1 + c);
    float2 ee = *(const float2*)(be1 + c);
    float rx = aA*rstd*gg.x + ee.x, ry = aB*rstd*gg.y + ee.y;
    h1b[(size_t)v*64 + lane] = (unsigned)f2bf(rx) | ((unsigned)f2bf(ry) << 16);
}

// ---------------- layer 2 linear via MFMA: h1b[N,128]bf16 @ W2[128,64] ----------------

__global__ __launch_bounds__(256) void k_lin2(
    const unsigned short* __restrict__ h1b,   // [N][128] bf16
    const float* __restrict__ W2,             // [128][64] fp32
    const float* __restrict__ asrc, const float* __restrict__ adst,
    unsigned short* __restrict__ hlin2b, float* __restrict__ es2, float* __restrict__ ed2, int N)
{
    int t = threadIdx.x, lane = t & 63, w = t >> 6;
    int vb = blockIdx.x * 64 + w * 16;
    if (vb >= N) return;
    int lo4 = lane & 15, hi4 = lane >> 4;

    int arow = vb + lo4; if (arow >= N) arow = N - 1;
    const unsigned short* ap = h1b + (size_t)arow*128 + hi4*8;
    bf16x8 a0 = *(const bf16x8*)(ap);
    bf16x8 a1 = *(const bf16x8*)(ap + 32);
    bf16x8 a2 = *(const bf16x8*)(ap + 64);
    bf16x8 a3 = *(const bf16x8*)(ap + 96);

    f32x4 acc[4];
    #pragma unroll
    for (int nt = 0; nt < 4; ++nt) acc[nt] = (f32x4){0.f, 0.f, 0.f, 0.f};

    #pragma unroll
    for (int nt = 0; nt < 4; ++nt){
        int cb = nt*16 + lo4;
        #pragma unroll
        for (int kt = 0; kt < 4; ++kt){
            const float* wp = W2 + (size_t)(kt*32 + hi4*8)*64 + cb;
            bf16x8 b;
            #pragma unroll
            for (int j = 0; j < 8; ++j) b[j] = (short)f2bf(wp[(size_t)j*64]);
            bf16x8 a = (kt==0) ? a0 : (kt==1) ? a1 : (kt==2) ? a2 : a3;
            acc[nt] = __builtin_amdgcn_mfma_f32_16x16x32_bf16(a, b, acc[nt], 0, 0, 0);
        }
    }

    float sa0 = asrc[lo4], sa1 = asrc[16+lo4], sa2 = asrc[32+lo4], sa3 = asrc[48+lo4];
    float sb0 = adst[lo4], sb1 = adst[16+lo4], sb2 = adst[32+lo4], sb3 = adst[48+lo4];

    #pragma unroll
    for (int reg = 0; reg < 4; ++reg){
        int nr = vb + hi4*4 + reg;
        bool ok = nr < N;
        float c0 = acc[0][reg], c1 = acc[1][reg], c2 = acc[2][reg], c3 = acc[3][reg];
        if (ok){
            unsigned short* hp = hlin2b + (size_t)nr*64 + lo4;
            hp[ 0] = f2bf(c0);
            hp[16] = f2bf(c1);
            hp[32] = f2bf(c2);
            hp[48] = f2bf(c3);
        }
        float ps0 = c0*sa0 + c1*sa1, ps1 = c2*sa2 + c3*sa3;
        float pd0 = c0*sb0 + c1*sb1, pd1 = c2*sb2 + c3*sb3;
        #pragma unroll
        for (int m = 8; m >= 1; m >>= 1){
            ps0 += __shfl_xor(ps0, m); ps1 += __shfl_xor(ps1, m);
            pd0 += __shfl_xor(pd0, m); pd1 += __shfl_xor(pd1, m);
        }
        if (ok && lo4 == 0){
            float2 e; e.x = ps0; e.y = ps1;
            float2 d; d.x = pd0; d.y = pd1;
            *(float2*)(es2 + (size_t)nr*2) = e;
            *(float2*)(ed2 + (size_t)nr*2) = d;
        }
    }
}

// ---------------- layer 2: fused attn+agg, EPG=4 with 4-edge batched gathers ----------------
// lane = (slot g = lane>>4, l = lane&15); lane covers channels 4l..4l+3 (head l>>3).

__global__ __launch_bounds__(256) void k_agg2(
    const unsigned* __restrict__ h2b,          // [N][32] u32 = bf16[N][64]
    const float* __restrict__ es2, const float* __restrict__ ed2,
    const int* __restrict__ row_ptr, const int* __restrict__ col,
    const float4* __restrict__ x4, const float* __restrict__ Wskip, const float* __restrict__ bskip,
    const float* __restrict__ b2, const float* __restrict__ g2, const float* __restrict__ be2,
    float* __restrict__ h2, int N)
{
    __shared__ float sp[4][2][68];
    int t = threadIdx.x, lane = t & 63, w = t >> 6;
    int v = blockIdx.x * 4 + w;
    if (v >= N) return;
    int g = lane >> 4, l = lane & 15;
    int hsel = l >> 3;
    float2 edv = *(const float2*)(ed2 + (size_t)v*2);
    float2 esv = *(const float2*)(es2 + (size_t)v*2);
    float eh = (hsel ? esv.y : esv.x) + (hsel ? edv.y : edv.x);
    float pself = (g == 0) ? __expf(lrelu(eh)) : 0.f;
    uint2 us = *(const uint2*)(h2b + (size_t)v*32 + l*2);
    float acc[4];
    acc[0] = pself * bf_lo(us.x);
    acc[1] = pself * bf_hi(us.x);
    acc[2] = pself * bf_lo(us.y);
    acc[3] = pself * bf_hi(us.y);
    float sum_p = pself;

    int beg = row_ptr[v], end = row_ptr[v+1];
    for (int base = beg; base < end; base += 64){
        int cnt = min(64, end - base);
        int sreg = 0;
        if (lane < cnt){
            sreg = col[base + lane];
            float2 q = *(const float2*)(es2 + (size_t)sreg*2);
            sp[w][0][lane] = __expf(lrelu(q.x + edv.x));
            sp[w][1][lane] = __expf(lrelu(q.y + edv.y));
        }
        asm volatile("s_waitcnt lgkmcnt(0)" ::: "memory");
        for (int i = 0; i < cnt; i += 16){
            int e0 = i + g, e1 = e0 + 4, e2 = e0 + 8, e3 = e0 + 12;
            int s0 = __shfl(sreg, e0), s1 = __shfl(sreg, e1);
            int s2 = __shfl(sreg, e2), s3 = __shfl(sreg, e3);
            bool v0 = e0 < cnt, v1 = e1 < cnt, v2 = e2 < cnt, v3 = e3 < cnt;
            if (!v0) s0 = v;  if (!v1) s1 = v;  if (!v2) s2 = v;  if (!v3) s3 = v;
            // issue all 4 independent gathers before any use
            uint2 u0 = *(const uint2*)(h2b + (size_t)s0*32 + l*2);
            uint2 u1 = *(const uint2*)(h2b + (size_t)s1*32 + l*2);
            uint2 u2 = *(const uint2*)(h2b + (size_t)s2*32 + l*2);
            uint2 u3 = *(const uint2*)(h2b + (size_t)s3*32 + l*2);
            float p0 = v0 ? sp[w][hsel][e0] : 0.f;
            float p1 = v1 ? sp[w][hsel][e1] : 0.f;
            float p2 = v2 ? sp[w][hsel][e2] : 0.f;
            float p3 = v3 ? sp[w][hsel][e3] : 0.f;
            sum_p += (p0 + p1) + (p2 + p3);
            acc[0] += p0*bf_lo(u0.x) + p1*bf_lo(u1.x) + p2*bf_lo(u2.x) + p3*bf_lo(u3.x);
            acc[1] += p0*bf_hi(u0.x) + p1*bf_hi(u1.x) + p2*bf_hi(u2.x) + p3*bf_hi(u3.x);
            acc[2] += p0*bf_lo(u0.y) + p1*bf_lo(u1.y) + p2*bf_lo(u2.y) + p3*bf_lo(u3.y);
            acc[3] += p0*bf_hi(u0.y) + p1*bf_hi(u1.y) + p2*bf_hi(u2.y) + p3*bf_hi(u3.y);
        }
    }
    #pragma unroll
    for (int j = 0; j < 4; ++j){
        acc[j] += __shfl_xor(acc[j], 16);
        acc[j] += __shfl_xor(acc[j], 32);
    }
    sum_p += __shfl_xor(sum_p, 16);
    sum_p += __shfl_xor(sum_p, 32);
    float inv = 1.f / (sum_p + 1e-16f);
    #pragma unroll
    for (int j = 0; j < 4; ++j) acc[j] *= inv;
    // head mean: lane l pairs with l^8 (channels c and c+32)
    float4 xv = x4[v];
    float xa = xv.x, xb = xv.y, xc = xv.z;
    int cc = (l & 7) * 4;
    float z[4];
    #pragma unroll
    for (int j = 0; j < 4; ++j){
        float other = __shfl_xor(acc[j], 8);
        float o = eluf(0.5f*(acc[j] + other) + b2[cc+j]);
        float sk = xa*Wskip[cc+j] + xb*Wskip[32+cc+j] + xc*Wskip[64+cc+j] + bskip[cc+j];
        z[j] = o + sk;
    }
    float su = z[0]+z[1]+z[2]+z[3];
    su += __shfl_xor(su,1); su += __shfl_xor(su,2); su += __shfl_xor(su,4);
    float mean = su * (1.f/32.f);
    float vs = 0.f;
    #pragma unroll
    for (int j = 0; j < 4; ++j){ float d = z[j]-mean; vs += d*d; }
    vs += __shfl_xor(vs,1); vs += __shfl_xor(vs,2); vs += __shfl_xor(vs,4);
    float rstd = rsqrtf(vs * (1.f/32.f) + LN_EPS);
    if (g == 0 && l < 8){
        float4 r;
        r.x = (z[0]-mean)*rstd*g2[cc  ] + be2[cc  ];
        r.y = (z[1]-mean)*rstd*g2[cc+1] + be2[cc+1];
        r.z = (z[2]-mean)*rstd*g2[cc+2] + be2[cc+2];
        r.w = (z[3]-mean)*rstd*g2[cc+3] + be2[cc+3];
        *(float4*)(h2 + (size_t)v*32 + cc) = r;
    }
}

// ---------------- pooling: per-graph mean/max/std (batch sorted) + projection ----------------

__global__ __launch_bounds__(256) void k_pool(
    const float* __restrict__ h2, const int* __restrict__ batch,
    const float* __restrict__ Wp, const float* __restrict__ bp,
    float* __restrict__ out, int N)
{
    int g = blockIdx.x; int t = threadIdx.x;
    __shared__ int sBeg, sEnd;
    if (t == 0){
        int lo = 0, hi = N;
        while (lo < hi){ int mid = (lo+hi) >> 1; if (batch[mid] < g) lo = mid+1; else hi = mid; }
        sBeg = lo;
        lo = sBeg; hi = N;
        while (lo < hi){ int mid = (lo+hi) >> 1; if (batch[mid] < g+1) lo = mid+1; else hi = mid; }
        sEnd = lo;
    }
    __syncthreads();
    int beg = sBeg, end = sEnd;
    int ch = t & 31, grp = t >> 5;
    float sum = 0.f, sq = 0.f, mx = -INFINITY;
    for (int i = beg + grp; i < end; i += 8){
        float val = h2[(size_t)i*32 + ch];
        sum += val; sq += val*val; mx = fmaxf(mx, val);
    }
    __shared__ float lsum[256], lsq[256], lmx[256];
    lsum[t] = sum; lsq[t] = sq; lmx[t] = mx;
    __syncthreads();
    for (int s = 4; s >= 1; s >>= 1){
        if (grp < s){
            lsum[t] += lsum[t + s*32];
            lsq [t] += lsq [t + s*32];
            lmx [t]  = fmaxf(lmx[t], lmx[t + s*32]);
        }
        __syncthreads();
    }
    __shared__ float feat[96];
    if (t < 32){
        float cnt = fmaxf((float)(end - beg), 1.f);
        float mean = lsum[t] / cnt;
        float var  = lsq[t] / cnt - mean*mean;
        feat[t]      = mean;
        feat[32 + t] = lmx[t];
        feat[64 + t] = sqrtf(fmaxf(var, 0.f));
    }
    __syncthreads();
    if (t < 48){
        float acc = bp[t];
        #pragma unroll 8
        for (int k = 0; k < 96; ++k) acc += feat[k] * Wp[k*48 + t];
        out[(size_t)g*48 + t] = acc;
    }
}

// ---------------- launcher ----------------

extern "C" void kernel_launch(void* const* d_in, const int* in_sizes, int n_in,
                              void* d_out, int out_size, void* d_ws, size_t ws_size,
                              hipStream_t stream)
{
    const float* x     = (const float*)d_in[0];
    const int*   ei    = (const int*)  d_in[1];
    const int*   batch = (const int*)  d_in[2];
    const float* W1    = (const float*)d_in[3];
    const float* as1   = (const float*)d_in[4];
    const float* ad1   = (const float*)d_in[5];
    const float* b1    = (const float*)d_in[6];
    const float* W2    = (const float*)d_in[7];
    const float* as2   = (const float*)d_in[8];
    const float* ad2   = (const float*)d_in[9];
    const float* b2    = (const float*)d_in[10];
    const float* Wskip = (const float*)d_in[11];
    const float* bskip = (const float*)d_in[12];
    const float* g1    = (const float*)d_in[13];
    const float* be1   = (const float*)d_in[14];
    const float* g2    = (const float*)d_in[15];
    const float* be2   = (const float*)d_in[16];
    const float* Wp    = (const float*)d_in[17];
    const float* bp    = (const float*)d_in[18];

    int N = in_sizes[0] / 3;
    int E = in_sizes[1] / 2;
    int B = out_size / 48;
    const int* src = ei;
    const int* dst = ei + E;
    int NBUK = (N + 63) / 64;
    int chunk = (E + NWG - 1) / NWG;
    int M = NBUK * NWG;

    char* w = (char*)d_ws;
    auto alloc = [&](size_t bytes) -> char* {
        char* p = w; w += (bytes + 255) & ~(size_t)255; return p;
    };
    int*   row_ptr = (int*)  alloc((size_t)(N+1)*4);
    int*   hist    = (int*)  alloc((size_t)M*4);
    int*   partial = (int*)  alloc(4*1024);
    int*   col     = (int*)  alloc((size_t)E*4);
    unsigned* h2b  = (unsigned*)alloc((size_t)N*32*4); // bf16[N][64] layer2 staging
    float* es      = (float*)alloc((size_t)N*4*4);
    float* ed      = (float*)alloc((size_t)N*4*4);
    unsigned* h1b  = (unsigned*)alloc((size_t)N*64*4); // bf16[N][128]
    float* h2      = (float*)alloc((size_t)N*32*4);
    float4* x4     = (float4*)alloc((size_t)N*16);
    unsigned* ebuf = (unsigned*)h2;                    // alias: ebuf dead before agg2 writes h2
    (void)ws_size;

    int mb  = (M + 255) / 256;
    int nb  = (N + 3) / 4;
    int nb2 = (N + 63) / 64;
    int npx = (N + 255) / 256;

    k_padx        <<<npx, 256, 0, stream>>>(x, x4, N);
    k_hist        <<<NWG, 512, 0, stream>>>(dst, hist, E, NBUK, chunk);
    k_chunk_sum   <<<mb, 256, 0, stream>>>(hist, partial, M);
    k_scan_partial<<<1, 512, 0, stream>>>(partial, mb);
    k_scan_apply  <<<mb, 256, 0, stream>>>(hist, partial, M);
    k_pscatter    <<<NWG, 512, 0, stream>>>(src, dst, hist, ebuf, E, NBUK, chunk);
    k_bfill       <<<(NBUK + 3) / 4, 256, 0, stream>>>(ebuf, hist, row_ptr, col, N, NBUK, E);

    k_lin1 <<<nb, 256, 0, stream>>>(x4, W1, as1, ad1, es, ed, N);
    k_agg1 <<<nb, 256, 0, stream>>>(x4, W1, es, ed, row_ptr, col, b1, g1, be1, h1b, N);
    k_lin2 <<<nb2, 256, 0, stream>>>((const unsigned short*)h1b, W2, as2, ad2,
                                     (unsigned short*)h2b, es, ed, N);
    k_agg2 <<<nb, 256, 0, stream>>>(h2b, es, ed, row_ptr, col,
                                    x4, Wskip, bskip, b2, g2, be2, h2, N);
    k_pool <<<B, 256, 0, stream>>>(h2, batch, Wp, bp, (float*)d_out, N);
}

// Round 11
// 275.963 us; speedup vs baseline: 1.2907x; 1.0608x over previous
//
#include <hip/hip_runtime.h>
#include <math.h>

#define NEG_SLOPE 0.2f
#define LN_EPS 1e-5f
#define NWG 256         // scatter workgroups; hist = [NB][NWG], 3-level scan

typedef __attribute__((ext_vector_type(8))) short bf16x8;
typedef __attribute__((ext_vector_type(4))) float f32x4;

__device__ __forceinline__ float lrelu(float v){ return v > 0.f ? v : NEG_SLOPE * v; }
__device__ __forceinline__ float eluf (float v){ return v > 0.f ? v : expm1f(v); }

__device__ __forceinline__ unsigned short f2bf(float f){
    unsigned x = __float_as_uint(f);
    unsigned r = (x + 0x7fffu + ((x >> 16) & 1u)) >> 16;   // round-nearest-even
    return (unsigned short)r;
}
__device__ __forceinline__ float bf_lo(unsigned u){ return __uint_as_float(u << 16); }
__device__ __forceinline__ float bf_hi(unsigned u){ return __uint_as_float(u & 0xffff0000u); }

// ---------------- pad x[N,3] -> xe[N] rows of 8 floats: [x0,x1,x2,0 | es0..es3] ----------------

__global__ void k_padx(const float* __restrict__ x, float* __restrict__ xe, int N){
    int v = blockIdx.x * 256 + threadIdx.x;
    if (v < N){
        float4 r;
        r.x = x[(size_t)v*3]; r.y = x[(size_t)v*3+1]; r.z = x[(size_t)v*3+2]; r.w = 0.f;
        *(float4*)(xe + (size_t)v*8) = r;
    }
}

// ---------------- bucketed CSR build, atomic-free scatter ----------------

__global__ __launch_bounds__(512) void k_hist(
    const int* __restrict__ dst, int* __restrict__ hist, int E, int NB, int chunk)
{
    __shared__ int cnt[2048];
    int t = threadIdx.x, w = blockIdx.x;
    for (int i = t; i < NB; i += 512) cnt[i] = 0;
    __syncthreads();
    int e0 = w * chunk, e1 = min(E, e0 + chunk);
    for (int e = e0 + t; e < e1; e += 512)
        atomicAdd(&cnt[dst[e] >> 6], 1);
    __syncthreads();
    for (int i = t; i < NB; i += 512)
        hist[(size_t)i * NWG + w] = cnt[i];
}

__global__ void k_chunk_sum(const int* __restrict__ data, int* __restrict__ partial, int M){
    __shared__ int lds[256];
    int t = threadIdx.x;
    int v = blockIdx.x * 256 + t;
    lds[t] = (v < M) ? data[v] : 0;
    __syncthreads();
    for (int s = 128; s > 0; s >>= 1){
        if (t < s) lds[t] += lds[t + s];
        __syncthreads();
    }
    if (t == 0) partial[blockIdx.x] = lds[0];
}

__global__ void k_scan_partial(int* __restrict__ partial, int n){
    __shared__ int lds[512];
    int t = threadIdx.x;
    int x = (t < n) ? partial[t] : 0;
    lds[t] = x;
    __syncthreads();
    for (int s = 1; s < 512; s <<= 1){
        int a = (t >= s) ? lds[t - s] : 0;
        __syncthreads();
        lds[t] += a;
        __syncthreads();
    }
    if (t < n) partial[t] = lds[t] - x;   // exclusive
}

__global__ void k_scan_apply(int* __restrict__ data, const int* __restrict__ partial, int M){
    __shared__ int lds[256];
    int t = threadIdx.x;
    int v = blockIdx.x * 256 + t;
    int x = (v < M) ? data[v] : 0;
    lds[t] = x;
    __syncthreads();
    for (int s = 1; s < 256; s <<= 1){
        int a = (t >= s) ? lds[t - s] : 0;
        __syncthreads();
        lds[t] += a;
        __syncthreads();
    }
    if (v < M) data[v] = partial[blockIdx.x] + lds[t] - x;   // exclusive
}

__global__ __launch_bounds__(512) void k_pscatter(
    const int* __restrict__ src, const int* __restrict__ dst,
    const int* __restrict__ shist, unsigned* __restrict__ ebuf, int E, int NB, int chunk)
{
    __shared__ int cur[2048];
    int t = threadIdx.x, w = blockIdx.x;
    for (int i = t; i < NB; i += 512) cur[i] = shist[(size_t)i * NWG + w];
    __syncthreads();
    int e0 = w * chunk, e1 = min(E, e0 + chunk);
    for (int e = e0 + t; e < e1; e += 512){
        int d = dst[e];
        int pos = atomicAdd(&cur[d >> 6], 1);
        ebuf[pos] = ((unsigned)(d & 63) << 26) | (unsigned)src[e];
    }
}

// one wave per bucket: local degree count -> wave-scan -> row_ptr + LDS-cursor fill
__global__ __launch_bounds__(256) void k_bfill(
    const unsigned* __restrict__ ebuf, const int* __restrict__ shist,
    int* __restrict__ row_ptr, int* __restrict__ col, int N, int NB, int E)
{
    __shared__ int scnt[4][64];
    int t = threadIdx.x, lane = t & 63, w = t >> 6;
    int b = blockIdx.x * 4 + w;
    bool act = b < NB;
    if (t == 0 && blockIdx.x == 0) row_ptr[N] = E;
    scnt[w][lane] = 0;
    __syncthreads();
    int ebeg = 0, eend = 0;
    if (act){
        ebeg = shist[(size_t)b * NWG];
        eend = (b + 1 < NB) ? shist[(size_t)(b + 1) * NWG] : E;
    }
    for (int j = ebeg + lane; j < eend; j += 64)
        atomicAdd(&scnt[w][ebuf[j] >> 26], 1);
    __syncthreads();
    int deg = scnt[w][lane];
    int incl = deg;
    #pragma unroll
    for (int k = 1; k < 64; k <<= 1){
        int up = __shfl_up(incl, k);
        if (lane >= k) incl += up;
    }
    int excl = incl - deg;
    int base = act ? ebeg : 0;
    int v = b * 64 + lane;
    if (act && v < N) row_ptr[v] = base + excl;
    __syncthreads();
    scnt[w][lane] = base + excl;
    __syncthreads();
    for (int j = ebeg + lane; j < eend; j += 64){
        unsigned u = ebuf[j];
        int pos = atomicAdd(&scnt[w][u >> 26], 1);
        col[pos] = (int)(u & 0x03FFFFFFu);
    }
}

// ---------------- layer 1 attention logits -> xe hi-half (es) + ed ----------------

__global__ __launch_bounds__(256) void k_lin1(
    float* __restrict__ xe, const float* __restrict__ W1,
    const float* __restrict__ asrc, const float* __restrict__ adst,
    float* __restrict__ ed, int N)
{
    __shared__ float sW[384], sA[128], sB[128];
    int t = threadIdx.x;
    for (int i = t; i < 384; i += 256) sW[i] = W1[i];
    for (int i = t; i < 128; i += 256){ sA[i] = asrc[i]; sB[i] = adst[i]; }
    __syncthreads();
    int lane = t & 63;
    int v = blockIdx.x * 4 + (t >> 6);
    if (v >= N) return;
    float4 xv = *(const float4*)(xe + (size_t)v*8);
    float x0 = xv.x, x1 = xv.y, x2 = xv.z;
    int c = lane * 2;
    float h0 = x0*sW[c  ] + x1*sW[128+c  ] + x2*sW[256+c  ];
    float h1 = x0*sW[c+1] + x1*sW[128+c+1] + x2*sW[256+c+1];
    int hsel = lane >> 4;
    float ts = h0*sA[c] + h1*sA[c+1];
    float td = h0*sB[c] + h1*sB[c+1];
    #pragma unroll
    for (int m = 8; m >= 1; m >>= 1){
        ts += __shfl_xor(ts, m); td += __shfl_xor(td, m);
    }
    if ((lane & 15) == 0){
        xe[(size_t)v*8 + 4 + hsel] = ts;    // es packed next to x
        ed[(size_t)v*4 + hsel] = td;
    }
}

// ---------------- layer 1: factored attn+agg, 2-deep pipeline, 1 line/edge ----------------
// sum_e p_e*(x[s]@W) = (sum_e p_e*x[s])@W ; xe row = [x0,x1,x2,0 | es0..3] (32 B)

__global__ __launch_bounds__(256) void k_agg1(
    const float* __restrict__ xe, const float* __restrict__ W1,
    const float* __restrict__ ed,
    const int* __restrict__ row_ptr, const int* __restrict__ col,
    const float* __restrict__ b1, const float* __restrict__ g1, const float* __restrict__ be1,
    unsigned* __restrict__ h1b, int N)
{
    int t = threadIdx.x, lane = t & 63, w = t >> 6;
    int v = blockIdx.x * 4 + w;
    if (v >= N) return;
    int hsel = lane >> 4, sub = lane & 15;
    float edh = ed[(size_t)v*4 + hsel];
    const float* qbase = xe + 4 + hsel;
    float sa0 = 0.f, sa1 = 0.f, sa2 = 0.f, sp_ = 0.f;
    int beg = row_ptr[v], end = row_ptr[v+1];
    int j = beg + sub;
    for (; j + 16 < end; j += 32){
        int sA = col[j], sB = col[j + 16];
        float4 a = *(const float4*)(xe + (size_t)sA*8);
        float4 b = *(const float4*)(xe + (size_t)sB*8);
        float qA = qbase[(size_t)sA*8];
        float qB = qbase[(size_t)sB*8];
        float pA = __expf(lrelu(qA + edh));
        float pB = __expf(lrelu(qB + edh));
        sp_ += pA + pB;
        sa0 += pA*a.x + pB*b.x;
        sa1 += pA*a.y + pB*b.y;
        sa2 += pA*a.z + pB*b.z;
    }
    if (j < end){
        int s = col[j];
        float4 a = *(const float4*)(xe + (size_t)s*8);
        float p = __expf(lrelu(qbase[(size_t)s*8] + edh));
        sp_ += p;
        sa0 += p*a.x; sa1 += p*a.y; sa2 += p*a.z;
    }
    if (sub == 0){   // self loop, once per head
        float4 a = *(const float4*)(xe + (size_t)v*8);
        float p = __expf(lrelu(qbase[(size_t)v*8] + edh));
        sp_ += p;
        sa0 += p*a.x; sa1 += p*a.y; sa2 += p*a.z;
    }
    #pragma unroll
    for (int k = 1; k < 16; k <<= 1){
        sa0 += __shfl_xor(sa0, k); sa1 += __shfl_xor(sa1, k);
        sa2 += __shfl_xor(sa2, k); sp_ += __shfl_xor(sp_, k);
    }
    float inv = 1.f / (sp_ + 1e-16f);
    float A0 = sa0*inv, A1 = sa1*inv, A2 = sa2*inv;
    int c = lane * 2;   // channels c,c+1 ; head (c>>5) == hsel
    float h0 = A0*W1[c  ] + A1*W1[128+c  ] + A2*W1[256+c  ];
    float h1v= A0*W1[c+1] + A1*W1[128+c+1] + A2*W1[256+c+1];
    float2 bb = *(const float2*)(b1 + c);
    float oA = eluf(h0 + bb.x);
    float oB = eluf(h1v + bb.y);
    float su = oA + oB;
    #pragma unroll
    for (int k = 32; k >= 1; k >>= 1) su += __shfl_xor(su, k);
    float mean = su * (1.f/128.f);
    float aA = oA - mean, aB = oB - mean;
    float vs = aA*aA + aB*aB;
    #pragma unroll
    for (int k = 32; k >= 1; k >>= 1) vs += __shfl_xor(vs, k);
    float rstd = rsqrtf(vs * (1.f/128.f) + LN_EPS);
    float2 gg = *(const float2*)(g1 + c);
    float2 ee = *(const float2*)(be1 + c);
    float rx = aA*rstd*gg.x + ee.x, ry = aB*rstd*gg.y + ee.y;
    h1b[(size_t)v*64 + lane] = (unsigned)f2bf(rx) | ((unsigned)f2bf(ry) << 16);
}

// ---------------- layer 2 linear via MFMA: h1b[N,128]bf16 @ W2[128,64] ----------------

__global__ __launch_bounds__(256) void k_lin2(
    const unsigned short* __restrict__ h1b,   // [N][128] bf16
    const float* __restrict__ W2,             // [128][64] fp32
    const float* __restrict__ asrc, const float* __restrict__ adst,
    unsigned short* __restrict__ hlin2b, float* __restrict__ es2, float* __restrict__ ed2, int N)
{
    int t = threadIdx.x, lane = t & 63, w = t >> 6;
    int vb = blockIdx.x * 64 + w * 16;
    if (vb >= N) return;
    int lo4 = lane & 15, hi4 = lane >> 4;

    int arow = vb + lo4; if (arow >= N) arow = N - 1;
    const unsigned short* ap = h1b + (size_t)arow*128 + hi4*8;
    bf16x8 a0 = *(const bf16x8*)(ap);
    bf16x8 a1 = *(const bf16x8*)(ap + 32);
    bf16x8 a2 = *(const bf16x8*)(ap + 64);
    bf16x8 a3 = *(const bf16x8*)(ap + 96);

    f32x4 acc[4];
    #pragma unroll
    for (int nt = 0; nt < 4; ++nt) acc[nt] = (f32x4){0.f, 0.f, 0.f, 0.f};

    #pragma unroll
    for (int nt = 0; nt < 4; ++nt){
        int cb = nt*16 + lo4;
        #pragma unroll
        for (int kt = 0; kt < 4; ++kt){
            const float* wp = W2 + (size_t)(kt*32 + hi4*8)*64 + cb;
            bf16x8 b;
            #pragma unroll
            for (int j = 0; j < 8; ++j) b[j] = (short)f2bf(wp[(size_t)j*64]);
            bf16x8 a = (kt==0) ? a0 : (kt==1) ? a1 : (kt==2) ? a2 : a3;
            acc[nt] = __builtin_amdgcn_mfma_f32_16x16x32_bf16(a, b, acc[nt], 0, 0, 0);
        }
    }

    float sa0 = asrc[lo4], sa1 = asrc[16+lo4], sa2 = asrc[32+lo4], sa3 = asrc[48+lo4];
    float sb0 = adst[lo4], sb1 = adst[16+lo4], sb2 = adst[32+lo4], sb3 = adst[48+lo4];

    #pragma unroll
    for (int reg = 0; reg < 4; ++reg){
        int nr = vb + hi4*4 + reg;
        bool ok = nr < N;
        float c0 = acc[0][reg], c1 = acc[1][reg], c2 = acc[2][reg], c3 = acc[3][reg];
        if (ok){
            unsigned short* hp = hlin2b + (size_t)nr*64 + lo4;
            hp[ 0] = f2bf(c0);
            hp[16] = f2bf(c1);
            hp[32] = f2bf(c2);
            hp[48] = f2bf(c3);
        }
        float ps0 = c0*sa0 + c1*sa1, ps1 = c2*sa2 + c3*sa3;
        float pd0 = c0*sb0 + c1*sb1, pd1 = c2*sb2 + c3*sb3;
        #pragma unroll
        for (int m = 8; m >= 1; m >>= 1){
            ps0 += __shfl_xor(ps0, m); ps1 += __shfl_xor(ps1, m);
            pd0 += __shfl_xor(pd0, m); pd1 += __shfl_xor(pd1, m);
        }
        if (ok && lo4 == 0){
            float2 e; e.x = ps0; e.y = ps1;
            float2 d; d.x = pd0; d.y = pd1;
            *(float2*)(es2 + (size_t)nr*2) = e;
            *(float2*)(ed2 + (size_t)nr*2) = d;
        }
    }
}

// ---------------- layer 2: fused attn+agg, EPG=4 with 4-edge batched gathers ----------------
// lane = (slot g = lane>>4, l = lane&15); lane covers channels 4l..4l+3 (head l>>3).

__global__ __launch_bounds__(256) void k_agg2(
    const unsigned* __restrict__ h2b,          // [N][32] u32 = bf16[N][64]
    const float* __restrict__ es2, const float* __restrict__ ed2,
    const int* __restrict__ row_ptr, const int* __restrict__ col,
    const float* __restrict__ xe, const float* __restrict__ Wskip, const float* __restrict__ bskip,
    const float* __restrict__ b2, const float* __restrict__ g2, const float* __restrict__ be2,
    float* __restrict__ h2, int N)
{
    __shared__ float sp[4][2][68];
    int t = threadIdx.x, lane = t & 63, w = t >> 6;
    int v = blockIdx.x * 4 + w;
    if (v >= N) return;
    int g = lane >> 4, l = lane & 15;
    int hsel = l >> 3;
    float2 edv = *(const float2*)(ed2 + (size_t)v*2);
    float2 esv = *(const float2*)(es2 + (size_t)v*2);
    float eh = (hsel ? esv.y : esv.x) + (hsel ? edv.y : edv.x);
    float pself = (g == 0) ? __expf(lrelu(eh)) : 0.f;
    uint2 us = *(const uint2*)(h2b + (size_t)v*32 + l*2);
    float acc[4];
    acc[0] = pself * bf_lo(us.x);
    acc[1] = pself * bf_hi(us.x);
    acc[2] = pself * bf_lo(us.y);
    acc[3] = pself * bf_hi(us.y);
    float sum_p = pself;

    int beg = row_ptr[v], end = row_ptr[v+1];
    for (int base = beg; base < end; base += 64){
        int cnt = min(64, end - base);
        int sreg = 0;
        if (lane < cnt){
            sreg = col[base + lane];
            float2 q = *(const float2*)(es2 + (size_t)sreg*2);
            sp[w][0][lane] = __expf(lrelu(q.x + edv.x));
            sp[w][1][lane] = __expf(lrelu(q.y + edv.y));
        }
        asm volatile("s_waitcnt lgkmcnt(0)" ::: "memory");
        for (int i = 0; i < cnt; i += 16){
            int e0 = i + g, e1 = e0 + 4, e2 = e0 + 8, e3 = e0 + 12;
            int s0 = __shfl(sreg, e0), s1 = __shfl(sreg, e1);
            int s2 = __shfl(sreg, e2), s3 = __shfl(sreg, e3);
            bool v0 = e0 < cnt, v1 = e1 < cnt, v2 = e2 < cnt, v3 = e3 < cnt;
            if (!v0) s0 = v;  if (!v1) s1 = v;  if (!v2) s2 = v;  if (!v3) s3 = v;
            // issue all 4 independent gathers before any use
            uint2 u0 = *(const uint2*)(h2b + (size_t)s0*32 + l*2);
            uint2 u1 = *(const uint2*)(h2b + (size_t)s1*32 + l*2);
            uint2 u2 = *(const uint2*)(h2b + (size_t)s2*32 + l*2);
            uint2 u3 = *(const uint2*)(h2b + (size_t)s3*32 + l*2);
            float p0 = v0 ? sp[w][hsel][e0] : 0.f;
            float p1 = v1 ? sp[w][hsel][e1] : 0.f;
            float p2 = v2 ? sp[w][hsel][e2] : 0.f;
            float p3 = v3 ? sp[w][hsel][e3] : 0.f;
            sum_p += (p0 + p1) + (p2 + p3);
            acc[0] += p0*bf_lo(u0.x) + p1*bf_lo(u1.x) + p2*bf_lo(u2.x) + p3*bf_lo(u3.x);
            acc[1] += p0*bf_hi(u0.x) + p1*bf_hi(u1.x) + p2*bf_hi(u2.x) + p3*bf_hi(u3.x);
            acc[2] += p0*bf_lo(u0.y) + p1*bf_lo(u1.y) + p2*bf_lo(u2.y) + p3*bf_lo(u3.y);
            acc[3] += p0*bf_hi(u0.y) + p1*bf_hi(u1.y) + p2*bf_hi(u2.y) + p3*bf_hi(u3.y);
        }
    }
    #pragma unroll
    for (int j = 0; j < 4; ++j){
        acc[j] += __shfl_xor(acc[j], 16);
        acc[j] += __shfl_xor(acc[j], 32);
    }
    sum_p += __shfl_xor(sum_p, 16);
    sum_p += __shfl_xor(sum_p, 32);
    float inv = 1.f / (sum_p + 1e-16f);
    #pragma unroll
    for (int j = 0; j < 4; ++j) acc[j] *= inv;
    // head mean: lane l pairs with l^8 (channels c and c+32)
    float4 xv = *(const float4*)(xe + (size_t)v*8);
    float xa = xv.x, xb = xv.y, xc = xv.z;
    int cc = (l & 7) * 4;
    float z[4];
    #pragma unroll
    for (int j = 0; j < 4; ++j){
        float other = __shfl_xor(acc[j], 8);
        float o = eluf(0.5f*(acc[j] + other) + b2[cc+j]);
        float sk = xa*Wskip[cc+j] + xb*Wskip[32+cc+j] + xc*Wskip[64+cc+j] + bskip[cc+j];
        z[j] = o + sk;
    }
    float su = z[0]+z[1]+z[2]+z[3];
    su += __shfl_xor(su,1); su += __shfl_xor(su,2); su += __shfl_xor(su,4);
    float mean = su * (1.f/32.f);
    float vs = 0.f;
    #pragma unroll
    for (int j = 0; j < 4; ++j){ float d = z[j]-mean; vs += d*d; }
    vs += __shfl_xor(vs,1); vs += __shfl_xor(vs,2); vs += __shfl_xor(vs,4);
    float rstd = rsqrtf(vs * (1.f/32.f) + LN_EPS);
    if (g == 0 && l < 8){
        float4 r;
        r.x = (z[0]-mean)*rstd*g2[cc  ] + be2[cc  ];
        r.y = (z[1]-mean)*rstd*g2[cc+1] + be2[cc+1];
        r.z = (z[2]-mean)*rstd*g2[cc+2] + be2[cc+2];
        r.w = (z[3]-mean)*rstd*g2[cc+3] + be2[cc+3];
        *(float4*)(h2 + (size_t)v*32 + cc) = r;
    }
}

// ---------------- pooling: per-graph mean/max/std (batch sorted) + projection ----------------

__global__ __launch_bounds__(256) void k_pool(
    const float* __restrict__ h2, const int* __restrict__ batch,
    const float* __restrict__ Wp, const float* __restrict__ bp,
    float* __restrict__ out, int N)
{
    int g = blockIdx.x; int t = threadIdx.x;
    __shared__ int sBeg, sEnd;
    if (t == 0){
        int lo = 0, hi = N;
        while (lo < hi){ int mid = (lo+hi) >> 1; if (batch[mid] < g) lo = mid+1; else hi = mid; }
        sBeg = lo;
        lo = sBeg; hi = N;
        while (lo < hi){ int mid = (lo+hi) >> 1; if (batch[mid] < g+1) lo = mid+1; else hi = mid; }
        sEnd = lo;
    }
    __syncthreads();
    int beg = sBeg, end = sEnd;
    int ch = t & 31, grp = t >> 5;
    float sum = 0.f, sq = 0.f, mx = -INFINITY;
    for (int i = beg + grp; i < end; i += 8){
        float val = h2[(size_t)i*32 + ch];
        sum += val; sq += val*val; mx = fmaxf(mx, val);
    }
    __shared__ float lsum[256], lsq[256], lmx[256];
    lsum[t] = sum; lsq[t] = sq; lmx[t] = mx;
    __syncthreads();
    for (int s = 4; s >= 1; s >>= 1){
        if (grp < s){
            lsum[t] += lsum[t + s*32];
            lsq [t] += lsq [t + s*32];
            lmx [t]  = fmaxf(lmx[t], lmx[t + s*32]);
        }
        __syncthreads();
    }
    __shared__ float feat[96];
    if (t < 32){
        float cnt = fmaxf((float)(end - beg), 1.f);
        float mean = lsum[t] / cnt;
        float var  = lsq[t] / cnt - mean*mean;
        feat[t]      = mean;
        feat[32 + t] = lmx[t];
        feat[64 + t] = sqrtf(fmaxf(var, 0.f));
    }
    __syncthreads();
    if (t < 48){
        float acc = bp[t];
        #pragma unroll 8
        for (int k = 0; k < 96; ++k) acc += feat[k] * Wp[k*48 + t];
        out[(size_t)g*48 + t] = acc;
    }
}

// ---------------- launcher ----------------

extern "C" void kernel_launch(void* const* d_in, const int* in_sizes, int n_in,
                              void* d_out, int out_size, void* d_ws, size_t ws_size,
                              hipStream_t stream)
{
    const float* x     = (const float*)d_in[0];
    const int*   ei    = (const int*)  d_in[1];
    const int*   batch = (const int*)  d_in[2];
    const float* W1    = (const float*)d_in[3];
    const float* as1   = (const float*)d_in[4];
    const float* ad1   = (const float*)d_in[5];
    const float* b1    = (const float*)d_in[6];
    const float* W2    = (const float*)d_in[7];
    const float* as2   = (const float*)d_in[8];
    const float* ad2   = (const float*)d_in[9];
    const float* b2    = (const float*)d_in[10];
    const float* Wskip = (const float*)d_in[11];
    const float* bskip = (const float*)d_in[12];
    const float* g1    = (const float*)d_in[13];
    const float* be1   = (const float*)d_in[14];
    const float* g2    = (const float*)d_in[15];
    const float* be2   = (const float*)d_in[16];
    const float* Wp    = (const float*)d_in[17];
    const float* bp    = (const float*)d_in[18];

    int N = in_sizes[0] / 3;
    int E = in_sizes[1] / 2;
    int B = out_size / 48;
    const int* src = ei;
    const int* dst = ei + E;
    int NBUK = (N + 63) / 64;              // 1563
    int chunk = (E + NWG - 1) / NWG;
    int M = NBUK * NWG;                    // 400128

    char* w = (char*)d_ws;
    auto alloc = [&](size_t bytes) -> char* {
        char* p = w; w += (bytes + 255) & ~(size_t)255; return p;
    };
    int*   row_ptr = (int*)  alloc((size_t)(N+1)*4);
    int*   hist    = (int*)  alloc((size_t)M*4);
    int*   p1      = (int*)  alloc(8*1024);            // level-1 partials (<=2048)
    int*   p2      = (int*)  alloc(4*1024);            // level-2 partials (<=512)
    int*   col     = (int*)  alloc((size_t)E*4);
    unsigned* h2b  = (unsigned*)alloc((size_t)N*32*4); // bf16[N][64] layer2 staging
    float* es      = (float*)alloc((size_t)N*4*4);     // layer2 es2 (N*2 used)
    float* ed      = (float*)alloc((size_t)N*4*4);     // layer1 ed (N*4) / layer2 ed2 (N*2)
    unsigned* h1b  = (unsigned*)alloc((size_t)N*64*4); // bf16[N][128]
    float* h2      = (float*)alloc((size_t)N*32*4);
    float* xe      = (float*)alloc((size_t)N*32);      // 8 floats per node
    unsigned* ebuf = (unsigned*)h2;                    // alias: ebuf dead before agg2 writes h2
    (void)ws_size;

    int mb  = (M + 255) / 256;             // 1563
    int mb2 = (mb + 255) / 256;            // 7
    int nb  = (N + 3) / 4;
    int nb2 = (N + 63) / 64;
    int npx = (N + 255) / 256;

    k_padx        <<<npx, 256, 0, stream>>>(x, xe, N);
    k_hist        <<<NWG, 512, 0, stream>>>(dst, hist, E, NBUK, chunk);
    k_chunk_sum   <<<mb, 256, 0, stream>>>(hist, p1, M);
    k_chunk_sum   <<<mb2, 256, 0, stream>>>(p1, p2, mb);
    k_scan_partial<<<1, 512, 0, stream>>>(p2, mb2);
    k_scan_apply  <<<mb2, 256, 0, stream>>>(p1, p2, mb);
    k_scan_apply  <<<mb, 256, 0, stream>>>(hist, p1, M);
    k_pscatter    <<<NWG, 512, 0, stream>>>(src, dst, hist, ebuf, E, NBUK, chunk);
    k_bfill       <<<(NBUK + 3) / 4, 256, 0, stream>>>(ebuf, hist, row_ptr, col, N, NBUK, E);

    k_lin1 <<<nb, 256, 0, stream>>>(xe, W1, as1, ad1, ed, N);
    k_agg1 <<<nb, 256, 0, stream>>>(xe, W1, ed, row_ptr, col, b1, g1, be1, h1b, N);
    k_lin2 <<<nb2, 256, 0, stream>>>((const unsigned short*)h1b, W2, as2, ad2,
                                     (unsigned short*)h2b, es, ed, N);
    k_agg2 <<<nb, 256, 0, stream>>>(h2b, es, ed, row_ptr, col,
                                    xe, Wskip, bskip, b2, g2, be2, h2, N);
    k_pool <<<B, 256, 0, stream>>>(h2, batch, Wp, bp, (float*)d_out, N);
}

// Round 12
// 253.353 us; speedup vs baseline: 1.4059x; 1.0892x over previous
//
#include <hip/hip_runtime.h>
#include <math.h>

#define NEG_SLOPE 0.2f
#define LN_EPS 1e-5f
#define NWG 256         // scatter workgroups; hist = [NB][NWG], 3-level scan

typedef __attribute__((ext_vector_type(8))) short bf16x8;
typedef __attribute__((ext_vector_type(4))) float f32x4;

__device__ __forceinline__ float lrelu(float v){ return v > 0.f ? v : NEG_SLOPE * v; }
__device__ __forceinline__ float eluf (float v){ return v > 0.f ? v : expm1f(v); }

__device__ __forceinline__ unsigned short f2bf(float f){
    unsigned x = __float_as_uint(f);
    unsigned r = (x + 0x7fffu + ((x >> 16) & 1u)) >> 16;   // round-nearest-even
    return (unsigned short)r;
}
__device__ __forceinline__ float bf_lo(unsigned u){ return __uint_as_float(u << 16); }
__device__ __forceinline__ float bf_hi(unsigned u){ return __uint_as_float(u & 0xffff0000u); }

// ---------------- pad x[N,3] -> x4[N] (16B aligned rows) ----------------

__global__ void k_padx(const float* __restrict__ x, float4* __restrict__ x4, int N){
    int v = blockIdx.x * 256 + threadIdx.x;
    if (v < N){
        float4 r;
        r.x = x[(size_t)v*3]; r.y = x[(size_t)v*3+1]; r.z = x[(size_t)v*3+2]; r.w = 0.f;
        x4[v] = r;
    }
}

// ---------------- bucketed CSR build, atomic-free scatter ----------------

__global__ __launch_bounds__(512) void k_hist(
    const int* __restrict__ dst, int* __restrict__ hist, int E, int NB, int chunk)
{
    __shared__ int cnt[2048];
    int t = threadIdx.x, w = blockIdx.x;
    for (int i = t; i < NB; i += 512) cnt[i] = 0;
    __syncthreads();
    int e0 = w * chunk, e1 = min(E, e0 + chunk);
    for (int e = e0 + t; e < e1; e += 512)
        atomicAdd(&cnt[dst[e] >> 6], 1);
    __syncthreads();
    for (int i = t; i < NB; i += 512)
        hist[(size_t)i * NWG + w] = cnt[i];
}

__global__ void k_chunk_sum(const int* __restrict__ data, int* __restrict__ partial, int M){
    __shared__ int lds[256];
    int t = threadIdx.x;
    int v = blockIdx.x * 256 + t;
    lds[t] = (v < M) ? data[v] : 0;
    __syncthreads();
    for (int s = 128; s > 0; s >>= 1){
        if (t < s) lds[t] += lds[t + s];
        __syncthreads();
    }
    if (t == 0) partial[blockIdx.x] = lds[0];
}

__global__ void k_scan_partial(int* __restrict__ partial, int n){
    __shared__ int lds[512];
    int t = threadIdx.x;
    int x = (t < n) ? partial[t] : 0;
    lds[t] = x;
    __syncthreads();
    for (int s = 1; s < 512; s <<= 1){
        int a = (t >= s) ? lds[t - s] : 0;
        __syncthreads();
        lds[t] += a;
        __syncthreads();
    }
    if (t < n) partial[t] = lds[t] - x;   // exclusive
}

__global__ void k_scan_apply(int* __restrict__ data, const int* __restrict__ partial, int M){
    __shared__ int lds[256];
    int t = threadIdx.x;
    int v = blockIdx.x * 256 + t;
    int x = (v < M) ? data[v] : 0;
    lds[t] = x;
    __syncthreads();
    for (int s = 1; s < 256; s <<= 1){
        int a = (t >= s) ? lds[t - s] : 0;
        __syncthreads();
        lds[t] += a;
        __syncthreads();
    }
    if (v < M) data[v] = partial[blockIdx.x] + lds[t] - x;   // exclusive
}

__global__ __launch_bounds__(512) void k_pscatter(
    const int* __restrict__ src, const int* __restrict__ dst,
    const int* __restrict__ shist, unsigned* __restrict__ ebuf, int E, int NB, int chunk)
{
    __shared__ int cur[2048];
    int t = threadIdx.x, w = blockIdx.x;
    for (int i = t; i < NB; i += 512) cur[i] = shist[(size_t)i * NWG + w];
    __syncthreads();
    int e0 = w * chunk, e1 = min(E, e0 + chunk);
    for (int e = e0 + t; e < e1; e += 512){
        int d = dst[e];
        int pos = atomicAdd(&cur[d >> 6], 1);
        ebuf[pos] = ((unsigned)(d & 63) << 26) | (unsigned)src[e];
    }
}

// one wave per bucket: local degree count -> wave-scan -> row_ptr + LDS-cursor fill
__global__ __launch_bounds__(256) void k_bfill(
    const unsigned* __restrict__ ebuf, const int* __restrict__ shist,
    int* __restrict__ row_ptr, int* __restrict__ col, int N, int NB, int E)
{
    __shared__ int scnt[4][64];
    int t = threadIdx.x, lane = t & 63, w = t >> 6;
    int b = blockIdx.x * 4 + w;
    bool act = b < NB;
    if (t == 0 && blockIdx.x == 0) row_ptr[N] = E;
    scnt[w][lane] = 0;
    __syncthreads();
    int ebeg = 0, eend = 0;
    if (act){
        ebeg = shist[(size_t)b * NWG];
        eend = (b + 1 < NB) ? shist[(size_t)(b + 1) * NWG] : E;
    }
    for (int j = ebeg + lane; j < eend; j += 64)
        atomicAdd(&scnt[w][ebuf[j] >> 26], 1);
    __syncthreads();
    int deg = scnt[w][lane];
    int incl = deg;
    #pragma unroll
    for (int k = 1; k < 64; k <<= 1){
        int up = __shfl_up(incl, k);
        if (lane >= k) incl += up;
    }
    int excl = incl - deg;
    int base = act ? ebeg : 0;
    int v = b * 64 + lane;
    if (act && v < N) row_ptr[v] = base + excl;
    __syncthreads();
    scnt[w][lane] = base + excl;
    __syncthreads();
    for (int j = ebeg + lane; j < eend; j += 64){
        unsigned u = ebuf[j];
        int pos = atomicAdd(&scnt[w][u >> 26], 1);
        col[pos] = (int)(u & 0x03FFFFFFu);
    }
}

// ---------------- layer 1: fused logits + attn + agg + bias + ELU + LN -> bf16 ----------------
// es[s] = x[s]·(W1 a_src) per head; ed[v] = x[v]·(W1 a_dst). No lin1 pass, no es array.
// sum_e p_e*(x[s]@W) = (sum_e p_e*x[s])@W ; lane = (head hsel=lane>>4, sub=lane&15)

__global__ __launch_bounds__(256) void k_agg1(
    const float4* __restrict__ x4, const float* __restrict__ W1,
    const float* __restrict__ as1, const float* __restrict__ ad1,
    const int* __restrict__ row_ptr, const int* __restrict__ col,
    const float* __restrict__ b1, const float* __restrict__ g1, const float* __restrict__ be1,
    unsigned* __restrict__ h1b, int N)
{
    __shared__ float sAW[24];   // [0..11]=asW[h*3+d], [12..23]=adW[h*3+d]
    int t = threadIdx.x, lane = t & 63, w = t >> 6;
    if (t < 24){
        int id = t % 12, h = id / 3, d = id % 3;
        const float* a = (t < 12) ? as1 : ad1;
        float s = 0.f;
        #pragma unroll 8
        for (int c = 0; c < 32; ++c) s += W1[d*128 + h*32 + c] * a[h*32 + c];
        sAW[t] = s;
    }
    __syncthreads();
    int v = blockIdx.x * 4 + w;
    if (v >= N) return;
    int hsel = lane >> 4, sub = lane & 15;
    float as0 = sAW[hsel*3], asv1 = sAW[hsel*3+1], as2 = sAW[hsel*3+2];
    float ad0 = sAW[12+hsel*3], adv1 = sAW[12+hsel*3+1], ad2 = sAW[12+hsel*3+2];
    float4 xv = x4[v];
    float edh = xv.x*ad0 + xv.y*adv1 + xv.z*ad2;
    float sa0 = 0.f, sa1 = 0.f, sa2 = 0.f, sp_ = 0.f;
    int beg = row_ptr[v], end = row_ptr[v+1];
    int j = beg + sub;
    for (; j + 16 < end; j += 32){
        int sA = col[j], sB = col[j + 16];
        float4 a = x4[sA];
        float4 b = x4[sB];
        float qA = a.x*as0 + a.y*asv1 + a.z*as2;
        float qB = b.x*as0 + b.y*asv1 + b.z*as2;
        float pA = __expf(lrelu(qA + edh));
        float pB = __expf(lrelu(qB + edh));
        sp_ += pA + pB;
        sa0 += pA*a.x + pB*b.x;
        sa1 += pA*a.y + pB*b.y;
        sa2 += pA*a.z + pB*b.z;
    }
    if (j < end){
        int s = col[j];
        float4 a = x4[s];
        float q = a.x*as0 + a.y*asv1 + a.z*as2;
        float p = __expf(lrelu(q + edh));
        sp_ += p;
        sa0 += p*a.x; sa1 += p*a.y; sa2 += p*a.z;
    }
    if (sub == 0){   // self loop, once per head
        float qs = xv.x*as0 + xv.y*asv1 + xv.z*as2;
        float p = __expf(lrelu(qs + edh));
        sp_ += p;
        sa0 += p*xv.x; sa1 += p*xv.y; sa2 += p*xv.z;
    }
    #pragma unroll
    for (int k = 1; k < 16; k <<= 1){
        sa0 += __shfl_xor(sa0, k); sa1 += __shfl_xor(sa1, k);
        sa2 += __shfl_xor(sa2, k); sp_ += __shfl_xor(sp_, k);
    }
    float inv = 1.f / (sp_ + 1e-16f);
    float A0 = sa0*inv, A1 = sa1*inv, A2 = sa2*inv;
    int c = lane * 2;   // channels c,c+1 ; head (c>>5) == hsel
    float h0 = A0*W1[c  ] + A1*W1[128+c  ] + A2*W1[256+c  ];
    float h1v= A0*W1[c+1] + A1*W1[128+c+1] + A2*W1[256+c+1];
    float2 bb = *(const float2*)(b1 + c);
    float oA = eluf(h0 + bb.x);
    float oB = eluf(h1v + bb.y);
    float su = oA + oB;
    #pragma unroll
    for (int k = 32; k >= 1; k >>= 1) su += __shfl_xor(su, k);
    float mean = su * (1.f/128.f);
    float aA = oA - mean, aB = oB - mean;
    float vs = aA*aA + aB*aB;
    #pragma unroll
    for (int k = 32; k >= 1; k >>= 1) vs += __shfl_xor(vs, k);
    float rstd = rsqrtf(vs * (1.f/128.f) + LN_EPS);
    float2 gg = *(const float2*)(g1 + c);
    float2 ee = *(const float2*)(be1 + c);
    float rx = aA*rstd*gg.x + ee.x, ry = aB*rstd*gg.y + ee.y;
    h1b[(size_t)v*64 + lane] = (unsigned)f2bf(rx) | ((unsigned)f2bf(ry) << 16);
}

// ---------------- layer 2 linear via MFMA: h1b[N,128]bf16 @ W2[128,64] -> fp8 ----------------

__global__ __launch_bounds__(256) void k_lin2(
    const unsigned short* __restrict__ h1b,   // [N][128] bf16
    const float* __restrict__ W2,             // [128][64] fp32
    const float* __restrict__ asrc, const float* __restrict__ adst,
    unsigned char* __restrict__ h2b8, float* __restrict__ es2, float* __restrict__ ed2, int N)
{
    int t = threadIdx.x, lane = t & 63, w = t >> 6;
    int vb = blockIdx.x * 64 + w * 16;
    if (vb >= N) return;
    int lo4 = lane & 15, hi4 = lane >> 4;

    int arow = vb + lo4; if (arow >= N) arow = N - 1;
    const unsigned short* ap = h1b + (size_t)arow*128 + hi4*8;
    bf16x8 a0 = *(const bf16x8*)(ap);
    bf16x8 a1 = *(const bf16x8*)(ap + 32);
    bf16x8 a2 = *(const bf16x8*)(ap + 64);
    bf16x8 a3 = *(const bf16x8*)(ap + 96);

    f32x4 acc[4];
    #pragma unroll
    for (int nt = 0; nt < 4; ++nt) acc[nt] = (f32x4){0.f, 0.f, 0.f, 0.f};

    #pragma unroll
    for (int nt = 0; nt < 4; ++nt){
        int cb = nt*16 + lo4;
        #pragma unroll
        for (int kt = 0; kt < 4; ++kt){
            const float* wp = W2 + (size_t)(kt*32 + hi4*8)*64 + cb;
            bf16x8 b;
            #pragma unroll
            for (int j = 0; j < 8; ++j) b[j] = (short)f2bf(wp[(size_t)j*64]);
            bf16x8 a = (kt==0) ? a0 : (kt==1) ? a1 : (kt==2) ? a2 : a3;
            acc[nt] = __builtin_amdgcn_mfma_f32_16x16x32_bf16(a, b, acc[nt], 0, 0, 0);
        }
    }

    float sa0 = asrc[lo4], sa1 = asrc[16+lo4], sa2 = asrc[32+lo4], sa3 = asrc[48+lo4];
    float sb0 = adst[lo4], sb1 = adst[16+lo4], sb2 = adst[32+lo4], sb3 = adst[48+lo4];

    #pragma unroll
    for (int reg = 0; reg < 4; ++reg){
        int nr = vb + hi4*4 + reg;
        bool ok = nr < N;
        float c0 = acc[0][reg], c1 = acc[1][reg], c2 = acc[2][reg], c3 = acc[3][reg];
        if (ok){
            int wv = __builtin_amdgcn_cvt_pk_fp8_f32(c0, c1, 0, false);
            wv = __builtin_amdgcn_cvt_pk_fp8_f32(c2, c3, wv, true);
            unsigned char* hp = h2b8 + (size_t)nr*64 + lo4;
            hp[ 0] = (unsigned char)( wv        & 255);
            hp[16] = (unsigned char)((wv >>  8) & 255);
            hp[32] = (unsigned char)((wv >> 16) & 255);
            hp[48] = (unsigned char)((wv >> 24) & 255);
        }
        float ps0 = c0*sa0 + c1*sa1, ps1 = c2*sa2 + c3*sa3;
        float pd0 = c0*sb0 + c1*sb1, pd1 = c2*sb2 + c3*sb3;
        #pragma unroll
        for (int m = 8; m >= 1; m >>= 1){
            ps0 += __shfl_xor(ps0, m); ps1 += __shfl_xor(ps1, m);
            pd0 += __shfl_xor(pd0, m); pd1 += __shfl_xor(pd1, m);
        }
        if (ok && lo4 == 0){
            float2 e; e.x = ps0; e.y = ps1;
            float2 d; d.x = pd0; d.y = pd1;
            *(float2*)(es2 + (size_t)nr*2) = e;
            *(float2*)(ed2 + (size_t)nr*2) = d;
        }
    }
}

// ---------------- layer 2: fused attn+agg, EPG=4, fp8 rows (1 line/edge) ----------------
// lane = (slot g = lane>>4, l = lane&15); lane covers channels 4l..4l+3 (head l>>3).

__global__ __launch_bounds__(256) void k_agg2(
    const unsigned* __restrict__ h2b,          // [N][16] u32 = fp8[N][64]
    const float* __restrict__ es2, const float* __restrict__ ed2,
    const int* __restrict__ row_ptr, const int* __restrict__ col,
    const float4* __restrict__ x4, const float* __restrict__ Wskip, const float* __restrict__ bskip,
    const float* __restrict__ b2, const float* __restrict__ g2, const float* __restrict__ be2,
    float* __restrict__ h2, int N)
{
    __shared__ float sp[4][2][68];
    int t = threadIdx.x, lane = t & 63, w = t >> 6;
    int v = blockIdx.x * 4 + w;
    if (v >= N) return;
    int g = lane >> 4, l = lane & 15;
    int hsel = l >> 3;
    float2 edv = *(const float2*)(ed2 + (size_t)v*2);
    float2 esv = *(const float2*)(es2 + (size_t)v*2);
    float eh = (hsel ? esv.y : esv.x) + (hsel ? edv.y : edv.x);
    float pself = (g == 0) ? __expf(lrelu(eh)) : 0.f;
    unsigned us = h2b[(size_t)v*16 + l];
    float acc[4];
    acc[0] = pself * __builtin_amdgcn_cvt_f32_fp8((int)us, 0);
    acc[1] = pself * __builtin_amdgcn_cvt_f32_fp8((int)us, 1);
    acc[2] = pself * __builtin_amdgcn_cvt_f32_fp8((int)us, 2);
    acc[3] = pself * __builtin_amdgcn_cvt_f32_fp8((int)us, 3);
    float sum_p = pself;

    int beg = row_ptr[v], end = row_ptr[v+1];
    for (int base = beg; base < end; base += 64){
        int cnt = min(64, end - base);
        int sreg = 0;
        if (lane < cnt){
            sreg = col[base + lane];
            float2 q = *(const float2*)(es2 + (size_t)sreg*2);
            sp[w][0][lane] = __expf(lrelu(q.x + edv.x));
            sp[w][1][lane] = __expf(lrelu(q.y + edv.y));
        }
        asm volatile("s_waitcnt lgkmcnt(0)" ::: "memory");
        for (int i = 0; i < cnt; i += 16){
            int e0 = i + g, e1 = e0 + 4, e2 = e0 + 8, e3 = e0 + 12;
            int s0 = __shfl(sreg, e0), s1 = __shfl(sreg, e1);
            int s2 = __shfl(sreg, e2), s3 = __shfl(sreg, e3);
            bool v0 = e0 < cnt, v1 = e1 < cnt, v2 = e2 < cnt, v3 = e3 < cnt;
            if (!v0) s0 = v;  if (!v1) s1 = v;  if (!v2) s2 = v;  if (!v3) s3 = v;
            // issue all 4 independent gathers before any use
            unsigned u0 = h2b[(size_t)s0*16 + l];
            unsigned u1 = h2b[(size_t)s1*16 + l];
            unsigned u2 = h2b[(size_t)s2*16 + l];
            unsigned u3 = h2b[(size_t)s3*16 + l];
            float p0 = v0 ? sp[w][hsel][e0] : 0.f;
            float p1 = v1 ? sp[w][hsel][e1] : 0.f;
            float p2 = v2 ? sp[w][hsel][e2] : 0.f;
            float p3 = v3 ? sp[w][hsel][e3] : 0.f;
            sum_p += (p0 + p1) + (p2 + p3);
            acc[0] += p0*__builtin_amdgcn_cvt_f32_fp8((int)u0, 0)
                    + p1*__builtin_amdgcn_cvt_f32_fp8((int)u1, 0)
                    + p2*__builtin_amdgcn_cvt_f32_fp8((int)u2, 0)
                    + p3*__builtin_amdgcn_cvt_f32_fp8((int)u3, 0);
            acc[1] += p0*__builtin_amdgcn_cvt_f32_fp8((int)u0, 1)
                    + p1*__builtin_amdgcn_cvt_f32_fp8((int)u1, 1)
                    + p2*__builtin_amdgcn_cvt_f32_fp8((int)u2, 1)
                    + p3*__builtin_amdgcn_cvt_f32_fp8((int)u3, 1);
            acc[2] += p0*__builtin_amdgcn_cvt_f32_fp8((int)u0, 2)
                    + p1*__builtin_amdgcn_cvt_f32_fp8((int)u1, 2)
                    + p2*__builtin_amdgcn_cvt_f32_fp8((int)u2, 2)
                    + p3*__builtin_amdgcn_cvt_f32_fp8((int)u3, 2);
            acc[3] += p0*__builtin_amdgcn_cvt_f32_fp8((int)u0, 3)
                    + p1*__builtin_amdgcn_cvt_f32_fp8((int)u1, 3)
                    + p2*__builtin_amdgcn_cvt_f32_fp8((int)u2, 3)
                    + p3*__builtin_amdgcn_cvt_f32_fp8((int)u3, 3);
        }
    }
    #pragma unroll
    for (int j = 0; j < 4; ++j){
        acc[j] += __shfl_xor(acc[j], 16);
        acc[j] += __shfl_xor(acc[j], 32);
    }
    sum_p += __shfl_xor(sum_p, 16);
    sum_p += __shfl_xor(sum_p, 32);
    float inv = 1.f / (sum_p + 1e-16f);
    #pragma unroll
    for (int j = 0; j < 4; ++j) acc[j] *= inv;
    // head mean: lane l pairs with l^8 (channels c and c+32)
    float4 xv = x4[v];
    float xa = xv.x, xb = xv.y, xc = xv.z;
    int cc = (l & 7) * 4;
    float z[4];
    #pragma unroll
    for (int j = 0; j < 4; ++j){
        float other = __shfl_xor(acc[j], 8);
        float o = eluf(0.5f*(acc[j] + other) + b2[cc+j]);
        float sk = xa*Wskip[cc+j] + xb*Wskip[32+cc+j] + xc*Wskip[64+cc+j] + bskip[cc+j];
        z[j] = o + sk;
    }
    float su = z[0]+z[1]+z[2]+z[3];
    su += __shfl_xor(su,1); su += __shfl_xor(su,2); su += __shfl_xor(su,4);
    float mean = su * (1.f/32.f);
    float vs = 0.f;
    #pragma unroll
    for (int j = 0; j < 4; ++j){ float d = z[j]-mean; vs += d*d; }
    vs += __shfl_xor(vs,1); vs += __shfl_xor(vs,2); vs += __shfl_xor(vs,4);
    float rstd = rsqrtf(vs * (1.f/32.f) + LN_EPS);
    if (g == 0 && l < 8){
        float4 r;
        r.x = (z[0]-mean)*rstd*g2[cc  ] + be2[cc  ];
        r.y = (z[1]-mean)*rstd*g2[cc+1] + be2[cc+1];
        r.z = (z[2]-mean)*rstd*g2[cc+2] + be2[cc+2];
        r.w = (z[3]-mean)*rstd*g2[cc+3] + be2[cc+3];
        *(float4*)(h2 + (size_t)v*32 + cc) = r;
    }
}

// ---------------- pooling: per-graph mean/max/std (batch sorted) + projection ----------------

__global__ __launch_bounds__(256) void k_pool(
    const float* __restrict__ h2, const int* __restrict__ batch,
    const float* __restrict__ Wp, const float* __restrict__ bp,
    float* __restrict__ out, int N)
{
    int g = blockIdx.x; int t = threadIdx.x;
    __shared__ int sBeg, sEnd;
    if (t == 0){
        int lo = 0, hi = N;
        while (lo < hi){ int mid = (lo+hi) >> 1; if (batch[mid] < g) lo = mid+1; else hi = mid; }
        sBeg = lo;
        lo = sBeg; hi = N;
        while (lo < hi){ int mid = (lo+hi) >> 1; if (batch[mid] < g+1) lo = mid+1; else hi = mid; }
        sEnd = lo;
    }
    __syncthreads();
    int beg = sBeg, end = sEnd;
    int ch = t & 31, grp = t >> 5;
    float sum = 0.f, sq = 0.f, mx = -INFINITY;
    for (int i = beg + grp; i < end; i += 8){
        float val = h2[(size_t)i*32 + ch];
        sum += val; sq += val*val; mx = fmaxf(mx, val);
    }
    __shared__ float lsum[256], lsq[256], lmx[256];
    lsum[t] = sum; lsq[t] = sq; lmx[t] = mx;
    __syncthreads();
    for (int s = 4; s >= 1; s >>= 1){
        if (grp < s){
            lsum[t] += lsum[t + s*32];
            lsq [t] += lsq [t + s*32];
            lmx [t]  = fmaxf(lmx[t], lmx[t + s*32]);
        }
        __syncthreads();
    }
    __shared__ float feat[96];
    if (t < 32){
        float cnt = fmaxf((float)(end - beg), 1.f);
        float mean = lsum[t] / cnt;
        float var  = lsq[t] / cnt - mean*mean;
        feat[t]      = mean;
        feat[32 + t] = lmx[t];
        feat[64 + t] = sqrtf(fmaxf(var, 0.f));
    }
    __syncthreads();
    if (t < 48){
        float acc = bp[t];
        #pragma unroll 8
        for (int k = 0; k < 96; ++k) acc += feat[k] * Wp[k*48 + t];
        out[(size_t)g*48 + t] = acc;
    }
}

// ---------------- launcher ----------------

extern "C" void kernel_launch(void* const* d_in, const int* in_sizes, int n_in,
                              void* d_out, int out_size, void* d_ws, size_t ws_size,
                              hipStream_t stream)
{
    const float* x     = (const float*)d_in[0];
    const int*   ei    = (const int*)  d_in[1];
    const int*   batch = (const int*)  d_in[2];
    const float* W1    = (const float*)d_in[3];
    const float* as1   = (const float*)d_in[4];
    const float* ad1   = (const float*)d_in[5];
    const float* b1    = (const float*)d_in[6];
    const float* W2    = (const float*)d_in[7];
    const float* as2   = (const float*)d_in[8];
    const float* ad2   = (const float*)d_in[9];
    const float* b2    = (const float*)d_in[10];
    const float* Wskip = (const float*)d_in[11];
    const float* bskip = (const float*)d_in[12];
    const float* g1    = (const float*)d_in[13];
    const float* be1   = (const float*)d_in[14];
    const float* g2    = (const float*)d_in[15];
    const float* be2   = (const float*)d_in[16];
    const float* Wp    = (const float*)d_in[17];
    const float* bp    = (const float*)d_in[18];

    int N = in_sizes[0] / 3;
    int E = in_sizes[1] / 2;
    int B = out_size / 48;
    const int* src = ei;
    const int* dst = ei + E;
    int NBUK = (N + 63) / 64;              // 1563
    int chunk = (E + NWG - 1) / NWG;
    int M = NBUK * NWG;                    // 400128

    char* w = (char*)d_ws;
    auto alloc = [&](size_t bytes) -> char* {
        char* p = w; w += (bytes + 255) & ~(size_t)255; return p;
    };
    int*   row_ptr = (int*)  alloc((size_t)(N+1)*4);
    int*   hist    = (int*)  alloc((size_t)M*4);
    int*   p1      = (int*)  alloc(8*1024);            // level-1 partials (<=2048)
    int*   p2      = (int*)  alloc(4*1024);            // level-2 partials (<=512)
    int*   col     = (int*)  alloc((size_t)E*4);
    unsigned* h2b  = (unsigned*)alloc((size_t)N*64);   // fp8[N][64]
    float* es      = (float*)alloc((size_t)N*2*4);     // layer2 es2
    float* ed      = (float*)alloc((size_t)N*2*4);     // layer2 ed2
    unsigned* h1b  = (unsigned*)alloc((size_t)N*64*4); // bf16[N][128]
    float* h2      = (float*)alloc((size_t)N*32*4);
    float4* x4     = (float4*)alloc((size_t)N*16);
    unsigned* ebuf = (unsigned*)h2;                    // alias: ebuf dead before agg2 writes h2
    (void)ws_size;

    int mb  = (M + 255) / 256;             // 1563
    int mb2 = (mb + 255) / 256;            // 7
    int nb  = (N + 3) / 4;
    int nb2 = (N + 63) / 64;
    int npx = (N + 255) / 256;

    k_padx        <<<npx, 256, 0, stream>>>(x, x4, N);
    k_hist        <<<NWG, 512, 0, stream>>>(dst, hist, E, NBUK, chunk);
    k_chunk_sum   <<<mb, 256, 0, stream>>>(hist, p1, M);
    k_chunk_sum   <<<mb2, 256, 0, stream>>>(p1, p2, mb);
    k_scan_partial<<<1, 512, 0, stream>>>(p2, mb2);
    k_scan_apply  <<<mb2, 256, 0, stream>>>(p1, p2, mb);
    k_scan_apply  <<<mb, 256, 0, stream>>>(hist, p1, M);
    k_pscatter    <<<NWG, 512, 0, stream>>>(src, dst, hist, ebuf, E, NBUK, chunk);
    k_bfill       <<<(NBUK + 3) / 4, 256, 0, stream>>>(ebuf, hist, row_ptr, col, N, NBUK, E);

    k_agg1 <<<nb, 256, 0, stream>>>(x4, W1, as1, ad1, row_ptr, col, b1, g1, be1, h1b, N);
    k_lin2 <<<nb2, 256, 0, stream>>>((const unsigned short*)h1b, W2, as2, ad2,
                                     (unsigned char*)h2b, es, ed, N);
    k_agg2 <<<nb, 256, 0, stream>>>(h2b, es, ed, row_ptr, col,
                                    x4, Wskip, bskip, b2, g2, be2, h2, N);
    k_pool <<<B, 256, 0, stream>>>(h2, batch, Wp, bp, (float*)d_out, N);
}

// Round 13
// 248.841 us; speedup vs baseline: 1.4314x; 1.0181x over previous
//
#include <hip/hip_runtime.h>
#include <math.h>

#define NEG_SLOPE 0.2f
#define LN_EPS 1e-5f
#define NWG 256         // scatter workgroups; hist = [NB][NWG], 3-level scan

typedef __attribute__((ext_vector_type(8))) short bf16x8;
typedef __attribute__((ext_vector_type(4))) float f32x4;
typedef __attribute__((ext_vector_type(2))) float f32x2;

__device__ __forceinline__ float lrelu(float v){ return v > 0.f ? v : NEG_SLOPE * v; }
__device__ __forceinline__ float eluf (float v){ return v > 0.f ? v : expm1f(v); }

__device__ __forceinline__ unsigned short f2bf(float f){
    unsigned x = __float_as_uint(f);
    unsigned r = (x + 0x7fffu + ((x >> 16) & 1u)) >> 16;   // round-nearest-even
    return (unsigned short)r;
}

// ---------------- bucketed CSR build, atomic-free scatter (padx folded in) ----------------

__global__ __launch_bounds__(512) void k_hist(
    const int* __restrict__ dst, int* __restrict__ hist,
    const float* __restrict__ x, float4* __restrict__ x4,
    int E, int NB, int chunk, int N)
{
    __shared__ int cnt[2048];
    int t = threadIdx.x, w = blockIdx.x;
    int gid = w * 512 + t;          // NWG*512 = 131072 >= N
    if (gid < N){
        float4 r;
        r.x = x[(size_t)gid*3]; r.y = x[(size_t)gid*3+1]; r.z = x[(size_t)gid*3+2]; r.w = 0.f;
        x4[gid] = r;
    }
    for (int i = t; i < NB; i += 512) cnt[i] = 0;
    __syncthreads();
    int e0 = w * chunk, e1 = min(E, e0 + chunk);
    for (int e = e0 + t; e < e1; e += 512)
        atomicAdd(&cnt[dst[e] >> 6], 1);
    __syncthreads();
    for (int i = t; i < NB; i += 512)
        hist[(size_t)i * NWG + w] = cnt[i];
}

__global__ void k_chunk_sum(const int* __restrict__ data, int* __restrict__ partial, int M){
    __shared__ int lds[256];
    int t = threadIdx.x;
    int v = blockIdx.x * 256 + t;
    lds[t] = (v < M) ? data[v] : 0;
    __syncthreads();
    for (int s = 128; s > 0; s >>= 1){
        if (t < s) lds[t] += lds[t + s];
        __syncthreads();
    }
    if (t == 0) partial[blockIdx.x] = lds[0];
}

__global__ void k_scan_partial(int* __restrict__ partial, int n){
    __shared__ int lds[512];
    int t = threadIdx.x;
    int x = (t < n) ? partial[t] : 0;
    lds[t] = x;
    __syncthreads();
    for (int s = 1; s < 512; s <<= 1){
        int a = (t >= s) ? lds[t - s] : 0;
        __syncthreads();
        lds[t] += a;
        __syncthreads();
    }
    if (t < n) partial[t] = lds[t] - x;   // exclusive
}

__global__ void k_scan_apply(int* __restrict__ data, const int* __restrict__ partial, int M){
    __shared__ int lds[256];
    int t = threadIdx.x;
    int v = blockIdx.x * 256 + t;
    int x = (v < M) ? data[v] : 0;
    lds[t] = x;
    __syncthreads();
    for (int s = 1; s < 256; s <<= 1){
        int a = (t >= s) ? lds[t - s] : 0;
        __syncthreads();
        lds[t] += a;
        __syncthreads();
    }
    if (v < M) data[v] = partial[blockIdx.x] + lds[t] - x;   // exclusive
}

__global__ __launch_bounds__(512) void k_pscatter(
    const int* __restrict__ src, const int* __restrict__ dst,
    const int* __restrict__ shist, unsigned* __restrict__ ebuf, int E, int NB, int chunk)
{
    __shared__ int cur[2048];
    int t = threadIdx.x, w = blockIdx.x;
    for (int i = t; i < NB; i += 512) cur[i] = shist[(size_t)i * NWG + w];
    __syncthreads();
    int e0 = w * chunk, e1 = min(E, e0 + chunk);
    for (int e = e0 + t; e < e1; e += 512){
        int d = dst[e];
        int pos = atomicAdd(&cur[d >> 6], 1);
        ebuf[pos] = ((unsigned)(d & 63) << 26) | (unsigned)src[e];
    }
}

// one wave per bucket: local degree count -> wave-scan -> row_ptr + LDS-cursor fill
__global__ __launch_bounds__(256) void k_bfill(
    const unsigned* __restrict__ ebuf, const int* __restrict__ shist,
    int* __restrict__ row_ptr, int* __restrict__ col, int N, int NB, int E)
{
    __shared__ int scnt[4][64];
    int t = threadIdx.x, lane = t & 63, w = t >> 6;
    int b = blockIdx.x * 4 + w;
    bool act = b < NB;
    if (t == 0 && blockIdx.x == 0) row_ptr[N] = E;
    scnt[w][lane] = 0;
    __syncthreads();
    int ebeg = 0, eend = 0;
    if (act){
        ebeg = shist[(size_t)b * NWG];
        eend = (b + 1 < NB) ? shist[(size_t)(b + 1) * NWG] : E;
    }
    for (int j = ebeg + lane; j < eend; j += 64)
        atomicAdd(&scnt[w][ebuf[j] >> 26], 1);
    __syncthreads();
    int deg = scnt[w][lane];
    int incl = deg;
    #pragma unroll
    for (int k = 1; k < 64; k <<= 1){
        int up = __shfl_up(incl, k);
        if (lane >= k) incl += up;
    }
    int excl = incl - deg;
    int base = act ? ebeg : 0;
    int v = b * 64 + lane;
    if (act && v < N) row_ptr[v] = base + excl;
    __syncthreads();
    scnt[w][lane] = base + excl;
    __syncthreads();
    for (int j = ebeg + lane; j < eend; j += 64){
        unsigned u = ebuf[j];
        int pos = atomicAdd(&scnt[w][u >> 26], 1);
        col[pos] = (int)(u & 0x03FFFFFFu);
    }
}

// ---------------- layer 1: fused logits + attn + agg + bias + ELU + LN -> bf16 ----------------
// es[s] = x[s]·(W1 a_src) per head; ed[v] = x[v]·(W1 a_dst). No lin1 pass, no es array.
// sum_e p_e*(x[s]@W) = (sum_e p_e*x[s])@W ; lane = (head hsel=lane>>4, sub=lane&15)

__global__ __launch_bounds__(256) void k_agg1(
    const float4* __restrict__ x4, const float* __restrict__ W1,
    const float* __restrict__ as1, const float* __restrict__ ad1,
    const int* __restrict__ row_ptr, const int* __restrict__ col,
    const float* __restrict__ b1, const float* __restrict__ g1, const float* __restrict__ be1,
    unsigned* __restrict__ h1b, int N)
{
    __shared__ float sAW[24];   // [0..11]=asW[h*3+d], [12..23]=adW[h*3+d]
    int t = threadIdx.x, lane = t & 63, w = t >> 6;
    if (t < 24){
        int id = t % 12, h = id / 3, d = id % 3;
        const float* a = (t < 12) ? as1 : ad1;
        float s = 0.f;
        #pragma unroll 8
        for (int c = 0; c < 32; ++c) s += W1[d*128 + h*32 + c] * a[h*32 + c];
        sAW[t] = s;
    }
    __syncthreads();
    int v = blockIdx.x * 4 + w;
    if (v >= N) return;
    int hsel = lane >> 4, sub = lane & 15;
    float as0 = sAW[hsel*3], asv1 = sAW[hsel*3+1], as2 = sAW[hsel*3+2];
    float ad0 = sAW[12+hsel*3], adv1 = sAW[12+hsel*3+1], ad2 = sAW[12+hsel*3+2];
    float4 xv = x4[v];
    float edh = xv.x*ad0 + xv.y*adv1 + xv.z*ad2;
    float sa0 = 0.f, sa1 = 0.f, sa2 = 0.f, sp_ = 0.f;
    int beg = row_ptr[v], end = row_ptr[v+1];
    int j = beg + sub;
    for (; j + 16 < end; j += 32){
        int sA = col[j], sB = col[j + 16];
        float4 a = x4[sA];
        float4 b = x4[sB];
        float qA = a.x*as0 + a.y*asv1 + a.z*as2;
        float qB = b.x*as0 + b.y*asv1 + b.z*as2;
        float pA = __expf(lrelu(qA + edh));
        float pB = __expf(lrelu(qB + edh));
        sp_ += pA + pB;
        sa0 += pA*a.x + pB*b.x;
        sa1 += pA*a.y + pB*b.y;
        sa2 += pA*a.z + pB*b.z;
    }
    if (j < end){
        int s = col[j];
        float4 a = x4[s];
        float q = a.x*as0 + a.y*asv1 + a.z*as2;
        float p = __expf(lrelu(q + edh));
        sp_ += p;
        sa0 += p*a.x; sa1 += p*a.y; sa2 += p*a.z;
    }
    if (sub == 0){   // self loop, once per head
        float qs = xv.x*as0 + xv.y*asv1 + xv.z*as2;
        float p = __expf(lrelu(qs + edh));
        sp_ += p;
        sa0 += p*xv.x; sa1 += p*xv.y; sa2 += p*xv.z;
    }
    #pragma unroll
    for (int k = 1; k < 16; k <<= 1){
        sa0 += __shfl_xor(sa0, k); sa1 += __shfl_xor(sa1, k);
        sa2 += __shfl_xor(sa2, k); sp_ += __shfl_xor(sp_, k);
    }
    float inv = 1.f / (sp_ + 1e-16f);
    float A0 = sa0*inv, A1 = sa1*inv, A2 = sa2*inv;
    int c = lane * 2;   // channels c,c+1 ; head (c>>5) == hsel
    float h0 = A0*W1[c  ] + A1*W1[128+c  ] + A2*W1[256+c  ];
    float h1v= A0*W1[c+1] + A1*W1[128+c+1] + A2*W1[256+c+1];
    float2 bb = *(const float2*)(b1 + c);
    float oA = eluf(h0 + bb.x);
    float oB = eluf(h1v + bb.y);
    float su = oA + oB;
    #pragma unroll
    for (int k = 32; k >= 1; k >>= 1) su += __shfl_xor(su, k);
    float mean = su * (1.f/128.f);
    float aA = oA - mean, aB = oB - mean;
    float vs = aA*aA + aB*aB;
    #pragma unroll
    for (int k = 32; k >= 1; k >>= 1) vs += __shfl_xor(vs, k);
    float rstd = rsqrtf(vs * (1.f/128.f) + LN_EPS);
    float2 gg = *(const float2*)(g1 + c);
    float2 ee = *(const float2*)(be1 + c);
    float rx = aA*rstd*gg.x + ee.x, ry = aB*rstd*gg.y + ee.y;
    h1b[(size_t)v*64 + lane] = (unsigned)f2bf(rx) | ((unsigned)f2bf(ry) << 16);
}

// ---------------- layer 2 linear via MFMA: h1b[N,128]bf16 @ W2[128,64] -> fp8 ----------------

__global__ __launch_bounds__(256) void k_lin2(
    const unsigned short* __restrict__ h1b,   // [N][128] bf16
    const float* __restrict__ W2,             // [128][64] fp32
    const float* __restrict__ asrc, const float* __restrict__ adst,
    unsigned char* __restrict__ h2b8, float* __restrict__ es2, float* __restrict__ ed2, int N)
{
    int t = threadIdx.x, lane = t & 63, w = t >> 6;
    int vb = blockIdx.x * 64 + w * 16;
    if (vb >= N) return;
    int lo4 = lane & 15, hi4 = lane >> 4;

    int arow = vb + lo4; if (arow >= N) arow = N - 1;
    const unsigned short* ap = h1b + (size_t)arow*128 + hi4*8;
    bf16x8 a0 = *(const bf16x8*)(ap);
    bf16x8 a1 = *(const bf16x8*)(ap + 32);
    bf16x8 a2 = *(const bf16x8*)(ap + 64);
    bf16x8 a3 = *(const bf16x8*)(ap + 96);

    f32x4 acc[4];
    #pragma unroll
    for (int nt = 0; nt < 4; ++nt) acc[nt] = (f32x4){0.f, 0.f, 0.f, 0.f};

    #pragma unroll
    for (int nt = 0; nt < 4; ++nt){
        int cb = nt*16 + lo4;
        #pragma unroll
        for (int kt = 0; kt < 4; ++kt){
            const float* wp = W2 + (size_t)(kt*32 + hi4*8)*64 + cb;
            bf16x8 b;
            #pragma unroll
            for (int j = 0; j < 8; ++j) b[j] = (short)f2bf(wp[(size_t)j*64]);
            bf16x8 a = (kt==0) ? a0 : (kt==1) ? a1 : (kt==2) ? a2 : a3;
            acc[nt] = __builtin_amdgcn_mfma_f32_16x16x32_bf16(a, b, acc[nt], 0, 0, 0);
        }
    }

    float sa0 = asrc[lo4], sa1 = asrc[16+lo4], sa2 = asrc[32+lo4], sa3 = asrc[48+lo4];
    float sb0 = adst[lo4], sb1 = adst[16+lo4], sb2 = adst[32+lo4], sb3 = adst[48+lo4];

    #pragma unroll
    for (int reg = 0; reg < 4; ++reg){
        int nr = vb + hi4*4 + reg;
        bool ok = nr < N;
        float c0 = acc[0][reg], c1 = acc[1][reg], c2 = acc[2][reg], c3 = acc[3][reg];
        if (ok){
            int wv = __builtin_amdgcn_cvt_pk_fp8_f32(c0, c1, 0, false);
            wv = __builtin_amdgcn_cvt_pk_fp8_f32(c2, c3, wv, true);
            unsigned char* hp = h2b8 + (size_t)nr*64 + lo4;
            hp[ 0] = (unsigned char)( wv        & 255);
            hp[16] = (unsigned char)((wv >>  8) & 255);
            hp[32] = (unsigned char)((wv >> 16) & 255);
            hp[48] = (unsigned char)((wv >> 24) & 255);
        }
        float ps0 = c0*sa0 + c1*sa1, ps1 = c2*sa2 + c3*sa3;
        float pd0 = c0*sb0 + c1*sb1, pd1 = c2*sb2 + c3*sb3;
        #pragma unroll
        for (int m = 8; m >= 1; m >>= 1){
            ps0 += __shfl_xor(ps0, m); ps1 += __shfl_xor(ps1, m);
            pd0 += __shfl_xor(pd0, m); pd1 += __shfl_xor(pd1, m);
        }
        if (ok && lo4 == 0){
            float2 e; e.x = ps0; e.y = ps1;
            float2 d; d.x = pd0; d.y = pd1;
            *(float2*)(es2 + (size_t)nr*2) = e;
            *(float2*)(ed2 + (size_t)nr*2) = d;
        }
    }
}

// ---------------- layer 2: fused attn+agg, EPG=4, fp8 rows, packed cvt/fma ----------------
// lane = (slot g = lane>>4, l = lane&15); lane covers channels 4l..4l+3 (head l>>3).

__global__ __launch_bounds__(256) void k_agg2(
    const unsigned* __restrict__ h2b,          // [N][16] u32 = fp8[N][64]
    const float* __restrict__ es2, const float* __restrict__ ed2,
    const int* __restrict__ row_ptr, const int* __restrict__ col,
    const float4* __restrict__ x4, const float* __restrict__ Wskip, const float* __restrict__ bskip,
    const float* __restrict__ b2, const float* __restrict__ g2, const float* __restrict__ be2,
    float* __restrict__ h2, int N)
{
    __shared__ float sp[4][2][68];
    int t = threadIdx.x, lane = t & 63, w = t >> 6;
    int v = blockIdx.x * 4 + w;
    if (v >= N) return;
    int g = lane >> 4, l = lane & 15;
    int hsel = l >> 3;
    float2 edv = *(const float2*)(ed2 + (size_t)v*2);
    float2 esv = *(const float2*)(es2 + (size_t)v*2);
    float eh = (hsel ? esv.y : esv.x) + (hsel ? edv.y : edv.x);
    float pself = (g == 0) ? __expf(lrelu(eh)) : 0.f;
    unsigned us = h2b[(size_t)v*16 + l];
    f32x2 acc01, acc23;
    {
        f32x2 slo = __builtin_amdgcn_cvt_pk_f32_fp8((int)us, false);
        f32x2 shi = __builtin_amdgcn_cvt_pk_f32_fp8((int)us, true);
        f32x2 ps = {pself, pself};
        acc01 = ps * slo;
        acc23 = ps * shi;
    }
    float sum_p = pself;

    int beg = row_ptr[v], end = row_ptr[v+1];
    for (int base = beg; base < end; base += 64){
        int cnt = min(64, end - base);
        int sreg = 0;
        if (lane < cnt){
            sreg = col[base + lane];
            float2 q = *(const float2*)(es2 + (size_t)sreg*2);
            sp[w][0][lane] = __expf(lrelu(q.x + edv.x));
            sp[w][1][lane] = __expf(lrelu(q.y + edv.y));
        }
        asm volatile("s_waitcnt lgkmcnt(0)" ::: "memory");
        for (int i = 0; i < cnt; i += 16){
            int e0 = i + g, e1 = e0 + 4, e2 = e0 + 8, e3 = e0 + 12;
            int s0 = __shfl(sreg, e0), s1 = __shfl(sreg, e1);
            int s2 = __shfl(sreg, e2), s3 = __shfl(sreg, e3);
            bool v0 = e0 < cnt, v1 = e1 < cnt, v2 = e2 < cnt, v3 = e3 < cnt;
            if (!v0) s0 = v;  if (!v1) s1 = v;  if (!v2) s2 = v;  if (!v3) s3 = v;
            // issue all 4 independent gathers before any use
            unsigned u0 = h2b[(size_t)s0*16 + l];
            unsigned u1 = h2b[(size_t)s1*16 + l];
            unsigned u2 = h2b[(size_t)s2*16 + l];
            unsigned u3 = h2b[(size_t)s3*16 + l];
            float p0 = v0 ? sp[w][hsel][e0] : 0.f;
            float p1 = v1 ? sp[w][hsel][e1] : 0.f;
            float p2 = v2 ? sp[w][hsel][e2] : 0.f;
            float p3 = v3 ? sp[w][hsel][e3] : 0.f;
            sum_p += (p0 + p1) + (p2 + p3);
            f32x2 p0v = {p0, p0}, p1v = {p1, p1}, p2v = {p2, p2}, p3v = {p3, p3};
            acc01 += p0v * __builtin_amdgcn_cvt_pk_f32_fp8((int)u0, false)
                   + p1v * __builtin_amdgcn_cvt_pk_f32_fp8((int)u1, false)
                   + p2v * __builtin_amdgcn_cvt_pk_f32_fp8((int)u2, false)
                   + p3v * __builtin_amdgcn_cvt_pk_f32_fp8((int)u3, false);
            acc23 += p0v * __builtin_amdgcn_cvt_pk_f32_fp8((int)u0, true)
                   + p1v * __builtin_amdgcn_cvt_pk_f32_fp8((int)u1, true)
                   + p2v * __builtin_amdgcn_cvt_pk_f32_fp8((int)u2, true)
                   + p3v * __builtin_amdgcn_cvt_pk_f32_fp8((int)u3, true);
        }
    }
    float acc[4] = {acc01.x, acc01.y, acc23.x, acc23.y};
    #pragma unroll
    for (int j = 0; j < 4; ++j){
        acc[j] += __shfl_xor(acc[j], 16);
        acc[j] += __shfl_xor(acc[j], 32);
    }
    sum_p += __shfl_xor(sum_p, 16);
    sum_p += __shfl_xor(sum_p, 32);
    float inv = 1.f / (sum_p + 1e-16f);
    #pragma unroll
    for (int j = 0; j < 4; ++j) acc[j] *= inv;
    // head mean: lane l pairs with l^8 (channels c and c+32)
    float4 xv = x4[v];
    float xa = xv.x, xb = xv.y, xc = xv.z;
    int cc = (l & 7) * 4;
    float z[4];
    #pragma unroll
    for (int j = 0; j < 4; ++j){
        float other = __shfl_xor(acc[j], 8);
        float o = eluf(0.5f*(acc[j] + other) + b2[cc+j]);
        float sk = xa*Wskip[cc+j] + xb*Wskip[32+cc+j] + xc*Wskip[64+cc+j] + bskip[cc+j];
        z[j] = o + sk;
    }
    float su = z[0]+z[1]+z[2]+z[3];
    su += __shfl_xor(su,1); su += __shfl_xor(su,2); su += __shfl_xor(su,4);
    float mean = su * (1.f/32.f);
    float vs = 0.f;
    #pragma unroll
    for (int j = 0; j < 4; ++j){ float d = z[j]-mean; vs += d*d; }
    vs += __shfl_xor(vs,1); vs += __shfl_xor(vs,2); vs += __shfl_xor(vs,4);
    float rstd = rsqrtf(vs * (1.f/32.f) + LN_EPS);
    if (g == 0 && l < 8){
        float4 r;
        r.x = (z[0]-mean)*rstd*g2[cc  ] + be2[cc  ];
        r.y = (z[1]-mean)*rstd*g2[cc+1] + be2[cc+1];
        r.z = (z[2]-mean)*rstd*g2[cc+2] + be2[cc+2];
        r.w = (z[3]-mean)*rstd*g2[cc+3] + be2[cc+3];
        *(float4*)(h2 + (size_t)v*32 + cc) = r;
    }
}

// ---------------- pooling: per-graph mean/max/std (batch sorted) + projection ----------------

__global__ __launch_bounds__(256) void k_pool(
    const float* __restrict__ h2, const int* __restrict__ batch,
    const float* __restrict__ Wp, const float* __restrict__ bp,
    float* __restrict__ out, int N)
{
    int g = blockIdx.x; int t = threadIdx.x;
    __shared__ int sBeg, sEnd;
    if (t == 0){
        int lo = 0, hi = N;
        while (lo < hi){ int mid = (lo+hi) >> 1; if (batch[mid] < g) lo = mid+1; else hi = mid; }
        sBeg = lo;
        lo = sBeg; hi = N;
        while (lo < hi){ int mid = (lo+hi) >> 1; if (batch[mid] < g+1) lo = mid+1; else hi = mid; }
        sEnd = lo;
    }
    __syncthreads();
    int beg = sBeg, end = sEnd;
    int ch = t & 31, grp = t >> 5;
    float sum = 0.f, sq = 0.f, mx = -INFINITY;
    for (int i = beg + grp; i < end; i += 8){
        float val = h2[(size_t)i*32 + ch];
        sum += val; sq += val*val; mx = fmaxf(mx, val);
    }
    __shared__ float lsum[256], lsq[256], lmx[256];
    lsum[t] = sum; lsq[t] = sq; lmx[t] = mx;
    __syncthreads();
    for (int s = 4; s >= 1; s >>= 1){
        if (grp < s){
            lsum[t] += lsum[t + s*32];
            lsq [t] += lsq [t + s*32];
            lmx [t]  = fmaxf(lmx[t], lmx[t + s*32]);
        }
        __syncthreads();
    }
    __shared__ float feat[96];
    if (t < 32){
        float cnt = fmaxf((float)(end - beg), 1.f);
        float mean = lsum[t] / cnt;
        float var  = lsq[t] / cnt - mean*mean;
        feat[t]      = mean;
        feat[32 + t] = lmx[t];
        feat[64 + t] = sqrtf(fmaxf(var, 0.f));
    }
    __syncthreads();
    if (t < 48){
        float acc = bp[t];
        #pragma unroll 8
        for (int k = 0; k < 96; ++k) acc += feat[k] * Wp[k*48 + t];
        out[(size_t)g*48 + t] = acc;
    }
}

// ---------------- launcher ----------------

extern "C" void kernel_launch(void* const* d_in, const int* in_sizes, int n_in,
                              void* d_out, int out_size, void* d_ws, size_t ws_size,
                              hipStream_t stream)
{
    const float* x     = (const float*)d_in[0];
    const int*   ei    = (const int*)  d_in[1];
    const int*   batch = (const int*)  d_in[2];
    const float* W1    = (const float*)d_in[3];
    const float* as1   = (const float*)d_in[4];
    const float* ad1   = (const float*)d_in[5];
    const float* b1    = (const float*)d_in[6];
    const float* W2    = (const float*)d_in[7];
    const float* as2   = (const float*)d_in[8];
    const float* ad2   = (const float*)d_in[9];
    const float* b2    = (const float*)d_in[10];
    const float* Wskip = (const float*)d_in[11];
    const float* bskip = (const float*)d_in[12];
    const float* g1    = (const float*)d_in[13];
    const float* be1   = (const float*)d_in[14];
    const float* g2    = (const float*)d_in[15];
    const float* be2   = (const float*)d_in[16];
    const float* Wp    = (const float*)d_in[17];
    const float* bp    = (const float*)d_in[18];

    int N = in_sizes[0] / 3;
    int E = in_sizes[1] / 2;
    int B = out_size / 48;
    const int* src = ei;
    const int* dst = ei + E;
    int NBUK = (N + 63) / 64;              // 1563
    int chunk = (E + NWG - 1) / NWG;
    int M = NBUK * NWG;                    // 400128

    char* w = (char*)d_ws;
    auto alloc = [&](size_t bytes) -> char* {
        char* p = w; w += (bytes + 255) & ~(size_t)255; return p;
    };
    int*   row_ptr = (int*)  alloc((size_t)(N+1)*4);
    int*   hist    = (int*)  alloc((size_t)M*4);
    int*   p1      = (int*)  alloc(8*1024);            // level-1 partials (<=2048)
    int*   p2      = (int*)  alloc(4*1024);            // level-2 partials (<=512)
    int*   col     = (int*)  alloc((size_t)E*4);
    unsigned* h2b  = (unsigned*)alloc((size_t)N*64);   // fp8[N][64]
    float* es      = (float*)alloc((size_t)N*2*4);     // layer2 es2
    float* ed      = (float*)alloc((size_t)N*2*4);     // layer2 ed2
    unsigned* h1b  = (unsigned*)alloc((size_t)N*64*4); // bf16[N][128]
    float* h2      = (float*)alloc((size_t)N*32*4);
    float4* x4     = (float4*)alloc((size_t)N*16);
    unsigned* ebuf = (unsigned*)h2;                    // alias: ebuf dead before agg2 writes h2
    (void)ws_size;

    int mb  = (M + 255) / 256;             // 1563
    int mb2 = (mb + 255) / 256;            // 7
    int nb  = (N + 3) / 4;
    int nb2 = (N + 63) / 64;

    k_hist        <<<NWG, 512, 0, stream>>>(dst, hist, x, x4, E, NBUK, chunk, N);
    k_chunk_sum   <<<mb, 256, 0, stream>>>(hist, p1, M);
    k_chunk_sum   <<<mb2, 256, 0, stream>>>(p1, p2, mb);
    k_scan_partial<<<1, 512, 0, stream>>>(p2, mb2);
    k_scan_apply  <<<mb2, 256, 0, stream>>>(p1, p2, mb);
    k_scan_apply  <<<mb, 256, 0, stream>>>(hist, p1, M);
    k_pscatter    <<<NWG, 512, 0, stream>>>(src, dst, hist, ebuf, E, NBUK, chunk);
    k_bfill       <<<(NBUK + 3) / 4, 256, 0, stream>>>(ebuf, hist, row_ptr, col, N, NBUK, E);

    k_agg1 <<<nb, 256, 0, stream>>>(x4, W1, as1, ad1, row_ptr, col, b1, g1, be1, h1b, N);
    k_lin2 <<<nb2, 256, 0, stream>>>((const unsigned short*)h1b, W2, as2, ad2,
                                     (unsigned char*)h2b, es, ed, N);
    k_agg2 <<<nb, 256, 0, stream>>>(h2b, es, ed, row_ptr, col,
                                    x4, Wskip, bskip, b2, g2, be2, h2, N);
    k_pool <<<B, 256, 0, stream>>>(h2, batch, Wp, bp, (float*)d_out, N);
}